// Round 2
// baseline (3762.427 us; speedup 1.0000x reference)
//
#include <hip/hip_runtime.h>
#include <math.h>

#define BB 8
#define IMGS 224
#define PSZ 16
#define CC 96
#define DEPTH 12
#define NCLS 43
#define HH 14
#define WW 14
#define LL 196
#define DD 192
#define NSTATE 16
#define RRANK 6
#define KDIR 4
#define DBLC 38   // R + 2N = 6 + 32

__device__ __forceinline__ float wave_sum(float v) {
#pragma unroll
  for (int m = 32; m; m >>= 1) v += __shfl_xor(v, m, 64);
  return v;
}

__device__ __forceinline__ float softplus_f(float x) {
  return (x > 20.f) ? x : log1pf(expf(x));
}

__device__ __forceinline__ float silu_f(float x) {
  return x / (1.f + expf(-x));
}

// source flat index into xc (B,D,L) row-major (h*W+w) for scan-direction k, position l
__device__ __forceinline__ int xs_src(int k, int l) {
  int lr = (k >= 2) ? (LL - 1 - l) : l;
  return (k & 1) ? ((lr % HH) * WW + lr / HH) : lr;
}

// ---------------- patch embed: conv16x16 stride16 + pos_embed -> t (B,L,C) ----------------
__global__ void k_patch(const float* __restrict__ x, const float* __restrict__ pw,
                        const float* __restrict__ pb, const float* __restrict__ pos,
                        float* __restrict__ t) {
  int idx = blockIdx.x * blockDim.x + threadIdx.x;
  if (idx >= BB * LL * CC) return;
  int c = idx % CC;
  int l = (idx / CC) % LL;
  int b = idx / (CC * LL);
  int ph = l / WW, pwc = l % WW;
  float acc = pb[c];
  for (int ci = 0; ci < 3; ci++)
    for (int kh = 0; kh < PSZ; kh++) {
      const float* xr = x + ((size_t)(b * 3 + ci) * IMGS + ph * PSZ + kh) * IMGS + pwc * PSZ;
      const float* wr = pw + ((size_t)(c * 3 + ci) * PSZ + kh) * PSZ;
      for (int kw = 0; kw < PSZ; kw++) acc += xr[kw] * wr[kw];
    }
  t[idx] = acc + pos[l * CC + c];
}

// ---------------- LayerNorm over C=96, one wave per token ----------------
__global__ void k_ln96(const float* __restrict__ in, const float* __restrict__ w,
                       const float* __restrict__ bias, float* __restrict__ out) {
  int tok = blockIdx.x;
  int lane = threadIdx.x;
  const float* p = in + (size_t)tok * CC;
  float v0 = p[lane];
  float v1 = (lane < CC - 64) ? p[lane + 64] : 0.f;
  float mu = wave_sum(v0 + v1) * (1.f / CC);
  float d0 = v0 - mu;
  float d1 = (lane < CC - 64) ? (v1 - mu) : 0.f;
  float var = wave_sum(d0 * d0 + d1 * d1) * (1.f / CC);
  float rs = rsqrtf(var + 1e-6f);
  out[(size_t)tok * CC + lane] = d0 * rs * w[lane] + bias[lane];
  if (lane < CC - 64)
    out[(size_t)tok * CC + lane + 64] = d1 * rs * w[lane + 64] + bias[lane + 64];
}

// ---------------- in_proj: (B,L,C) x (C,2D) -> xz (B,L,2D) ----------------
__global__ void k_inproj(const float* __restrict__ xln, const float* __restrict__ ipw,
                         float* __restrict__ xz) {
  int idx = blockIdx.x * blockDim.x + threadIdx.x;
  if (idx >= BB * LL * 2 * DD) return;
  int j = idx % (2 * DD);
  int tok = idx / (2 * DD);
  const float* p = xln + (size_t)tok * CC;
  float acc = 0.f;
  for (int c = 0; c < CC; c++) acc += p[c] * ipw[(size_t)c * (2 * DD) + j];
  xz[idx] = acc;
}

// ---------------- depthwise 3x3 SAME conv + bias + SiLU -> xc (B,D,L) ----------------
__global__ void k_conv(const float* __restrict__ xz, const float* __restrict__ cw,
                       const float* __restrict__ cb, float* __restrict__ xc) {
  int idx = blockIdx.x * blockDim.x + threadIdx.x;
  if (idx >= BB * DD * LL) return;
  int l = idx % LL;
  int d = (idx / LL) % DD;
  int b = idx / (LL * DD);
  int h = l / WW, w = l % WW;
  float acc = cb[d];
  for (int kh = 0; kh < 3; kh++) {
    int hh = h + kh - 1;
    if (hh < 0 || hh >= HH) continue;
    for (int kw = 0; kw < 3; kw++) {
      int ww = w + kw - 1;
      if (ww < 0 || ww >= WW) continue;
      acc += xz[((size_t)(b * LL + hh * WW + ww)) * (2 * DD) + d] * cw[d * 9 + kh * 3 + kw];
    }
  }
  xc[idx] = silu_f(acc);
}

// ---------------- x_proj: dbl[b,k,l,c] = sum_d xs[b,k,d,l] * xpw[k,c,d] ----------------
__global__ void k_xproj(const float* __restrict__ xc, const float* __restrict__ xpw,
                        float* __restrict__ dbl) {
  int idx = blockIdx.x * blockDim.x + threadIdx.x;
  if (idx >= BB * KDIR * LL * DBLC) return;
  int c = idx % DBLC;
  int l = (idx / DBLC) % LL;
  int k = (idx / (DBLC * LL)) % KDIR;
  int b = idx / (DBLC * LL * KDIR);
  int src = xs_src(k, l);
  const float* xcb = xc + (size_t)b * DD * LL + src;
  const float* wp = xpw + ((size_t)k * DBLC + c) * DD;
  float acc = 0.f;
  for (int d = 0; d < DD; d++) acc += xcb[(size_t)d * LL] * wp[d];
  dbl[idx] = acc;
}

// ---------------- selective scan (fused dt_proj + merge-scatter) ----------------
// lane = state n (0..15); group of 16 lanes = one (b,k,d) chain.
// dt computed inline; output atomically merged into ym (B,L,D) at lo = xs_src(k,l).
__global__ void k_scan(const float* __restrict__ xc, const float* __restrict__ dbl,
                       const float* __restrict__ dtw, const float* __restrict__ dtb,
                       const float* __restrict__ alog, const float* __restrict__ dsv,
                       float* __restrict__ ym) {
  int tid = blockIdx.x * blockDim.x + threadIdx.x;
  int n = tid & 15;
  int g = tid >> 4;  // (b*K + k)*D + d
  if (g >= BB * KDIR * DD) return;
  int d = g % DD;
  int k = (g / DD) % KDIR;
  int b = g / (DD * KDIR);
  float A = -expf(alog[((size_t)k * DD + d) * NSTATE + n]);
  float Dsc = dsv[k * DD + d];
  const float* wp = dtw + ((size_t)k * DD + d) * RRANK;
  float w0 = wp[0], w1 = wp[1], w2 = wp[2], w3 = wp[3], w4 = wp[4], w5 = wp[5];
  float dtbias = dtb[k * DD + d];
  const float* blp = dbl + (size_t)(b * KDIR + k) * LL * DBLC;
  const float* xcb = xc + (size_t)b * DD * LL + (size_t)d * LL;
  float* yo = ym + (size_t)b * LL * DD;
  float h = 0.f;
  for (int l = 0; l < LL; l++) {
    const float* q = blp + (size_t)l * DBLC;
    float dtl = dtbias + q[0] * w0 + q[1] * w1 + q[2] * w2 + q[3] * w3 + q[4] * w4 + q[5] * w5;
    dtl = softplus_f(dtl);
    int src = xs_src(k, l);
    float xv = xcb[src];
    float Bn = q[6 + n];
    float Cn = q[22 + n];
    h = h * expf(dtl * A) + dtl * xv * Bn;
    float part = h * Cn;
    part += __shfl_xor(part, 1, 64);
    part += __shfl_xor(part, 2, 64);
    part += __shfl_xor(part, 4, 64);
    part += __shfl_xor(part, 8, 64);
    if (n == 0) atomicAdd(&yo[(size_t)src * DD + d], part + Dsc * xv);
  }
}

// ---------------- out_norm (LN over D=192) * silu(z) -> g (B,L,D); one wave/token ----------------
__global__ void k_lngate(const float* __restrict__ ym, const float* __restrict__ onw,
                         const float* __restrict__ onb, const float* __restrict__ xz,
                         float* __restrict__ g) {
  int tok = blockIdx.x;
  int lane = threadIdx.x;
  const float* p = ym + (size_t)tok * DD;
  float v0 = p[lane], v1 = p[lane + 64], v2 = p[lane + 128];
  float mu = wave_sum(v0 + v1 + v2) * (1.f / DD);
  float d0 = v0 - mu, d1 = v1 - mu, d2 = v2 - mu;
  float var = wave_sum(d0 * d0 + d1 * d1 + d2 * d2) * (1.f / DD);
  float rs = rsqrtf(var + 1e-6f);
  const float* zp = xz + (size_t)tok * 2 * DD + DD;
  float* go = g + (size_t)tok * DD;
  go[lane]       = (d0 * rs * onw[lane] + onb[lane]) * silu_f(zp[lane]);
  go[lane + 64]  = (d1 * rs * onw[lane + 64] + onb[lane + 64]) * silu_f(zp[lane + 64]);
  go[lane + 128] = (d2 * rs * onw[lane + 128] + onb[lane + 128]) * silu_f(zp[lane + 128]);
}

// ---------------- out_proj + residual: t[b,l,c] += sum_d g*opw ----------------
__global__ void k_outproj(const float* __restrict__ g, const float* __restrict__ opw,
                          float* __restrict__ t) {
  int idx = blockIdx.x * blockDim.x + threadIdx.x;
  if (idx >= BB * LL * CC) return;
  int c = idx % CC;
  int tok = idx / CC;
  const float* gp = g + (size_t)tok * DD;
  float acc = 0.f;
  for (int d = 0; d < DD; d++) acc += gp[d] * opw[(size_t)d * CC + c];
  t[idx] += acc;
}

// ---------------- final mean-pool over L ----------------
__global__ void k_pool(const float* __restrict__ tf, float* __restrict__ pooled) {
  int idx = blockIdx.x * blockDim.x + threadIdx.x;
  if (idx >= BB * CC) return;
  int c = idx % CC;
  int b = idx / CC;
  float acc = 0.f;
  for (int l = 0; l < LL; l++) acc += tf[((size_t)b * LL + l) * CC + c];
  pooled[idx] = acc * (1.f / LL);
}

// ---------------- head ----------------
__global__ void k_head(const float* __restrict__ pooled, const float* __restrict__ hw,
                       const float* __restrict__ hb, float* __restrict__ out) {
  int idx = blockIdx.x * blockDim.x + threadIdx.x;
  if (idx >= BB * NCLS) return;
  int j = idx % NCLS;
  int b = idx / NCLS;
  float acc = hb[j];
  for (int c = 0; c < CC; c++) acc += pooled[b * CC + c] * hw[c * NCLS + j];
  out[idx] = acc;
}

extern "C" void kernel_launch(void* const* d_in, const int* in_sizes, int n_in,
                              void* d_out, int out_size, void* d_ws, size_t ws_size,
                              hipStream_t stream) {
  const float* x       = (const float*)d_in[0];
  const float* patch_w = (const float*)d_in[1];
  const float* patch_b = (const float*)d_in[2];
  const float* pos     = (const float*)d_in[3];
  const float* ln1_w   = (const float*)d_in[4];
  const float* ln1_b   = (const float*)d_in[5];
  const float* ipw     = (const float*)d_in[6];
  const float* cw      = (const float*)d_in[7];
  const float* cb      = (const float*)d_in[8];
  const float* xpw     = (const float*)d_in[9];
  const float* dtw     = (const float*)d_in[10];
  const float* dtb     = (const float*)d_in[11];
  const float* alog    = (const float*)d_in[12];
  const float* dsp     = (const float*)d_in[13];
  const float* onw     = (const float*)d_in[14];
  const float* onb     = (const float*)d_in[15];
  const float* opw     = (const float*)d_in[16];
  const float* nw      = (const float*)d_in[17];
  const float* nb      = (const float*)d_in[18];
  const float* hw      = (const float*)d_in[19];
  const float* hb      = (const float*)d_in[20];
  float* out = (float*)d_out;

  // Workspace layout — total 1,743,616 floats = 6.97 MB (was 18.4 MB; likely ws overflow -> abort)
  float* wsf  = (float*)d_ws;
  float* t    = wsf;                           // B*L*C    = 150528
  float* xln  = t    + BB * LL * CC;           // 150528   (reused as tf at end)
  float* xz   = xln  + BB * LL * CC;           // B*L*2D   = 602112
  float* xc   = xz   + BB * LL * 2 * DD;       // B*D*L    = 301056  (reused as gbuf post-scan)
  float* dbl  = xc   + BB * DD * LL;           // B*K*L*38 = 238336  (reused as pooled at end)
  float* ym   = dbl  + BB * KDIR * LL * DBLC;  // B*L*D    = 301056
  float* gbuf = xc;                            // alias: xc dead after scan
  float* tf   = xln;                           // alias: xln dead after last layer
  float* pooled = dbl;                         // alias: dbl dead after last layer

  k_patch<<<(BB * LL * CC + 255) / 256, 256, 0, stream>>>(x, patch_w, patch_b, pos, t);

  for (int i = 0; i < DEPTH; i++) {
    k_ln96<<<BB * LL, 64, 0, stream>>>(t, ln1_w + i * CC, ln1_b + i * CC, xln);
    k_inproj<<<(BB * LL * 2 * DD + 255) / 256, 256, 0, stream>>>(
        xln, ipw + (size_t)i * CC * 2 * DD, xz);
    k_conv<<<(BB * DD * LL + 255) / 256, 256, 0, stream>>>(xz, cw + i * DD * 9, cb + i * DD, xc);
    k_xproj<<<(BB * KDIR * LL * DBLC + 255) / 256, 256, 0, stream>>>(
        xc, xpw + (size_t)i * KDIR * DBLC * DD, dbl);
    hipMemsetAsync(ym, 0, (size_t)BB * LL * DD * sizeof(float), stream);
    k_scan<<<(BB * KDIR * DD * 16 + 255) / 256, 256, 0, stream>>>(
        xc, dbl, dtw + (size_t)i * KDIR * DD * RRANK, dtb + i * KDIR * DD,
        alog + (size_t)i * KDIR * DD * NSTATE, dsp + i * KDIR * DD, ym);
    k_lngate<<<BB * LL, 64, 0, stream>>>(ym, onw + i * DD, onb + i * DD, xz, gbuf);
    k_outproj<<<(BB * LL * CC + 255) / 256, 256, 0, stream>>>(gbuf, opw + (size_t)i * DD * CC, t);
  }

  k_ln96<<<BB * LL, 64, 0, stream>>>(t, nw, nb, tf);
  k_pool<<<(BB * CC + 255) / 256, 256, 0, stream>>>(tf, pooled);
  k_head<<<(BB * NCLS + 255) / 256, 256, 0, stream>>>(pooled, hw, hb, out);
}

// Round 3
// 2968.651 us; speedup vs baseline: 1.2674x; 1.2674x over previous
//
#include <hip/hip_runtime.h>
#include <math.h>

#define BB 8
#define IMGS 224
#define PSZ 16
#define CC 96
#define DEPTH 12
#define NCLS 43
#define HH 14
#define WW 14
#define LL 196
#define DD 192
#define NSTATE 16
#define RRANK 6
#define KDIR 4
#define DBLC 38   // R + 2N = 6 + 32
#define SEG 49    // L / 4 segments per chain (one 16-lane group each)

__device__ __forceinline__ float wave_sum(float v) {
#pragma unroll
  for (int m = 32; m; m >>= 1) v += __shfl_xor(v, m, 64);
  return v;
}

__device__ __forceinline__ float softplus_f(float x) {
  return (x > 20.f) ? x : log1pf(expf(x));
}

__device__ __forceinline__ float silu_f(float x) {
  return x / (1.f + expf(-x));
}

// source flat index into xc (B,D,L) row-major (h*W+w) for scan-direction k, position l
__device__ __forceinline__ int xs_src(int k, int l) {
  int lr = (k >= 2) ? (LL - 1 - l) : l;
  return (k & 1) ? ((lr % HH) * WW + lr / HH) : lr;
}

// ---------------- patch embed: conv16x16 stride16 + pos_embed -> t (B,L,C) ----------------
__global__ void k_patch(const float* __restrict__ x, const float* __restrict__ pw,
                        const float* __restrict__ pb, const float* __restrict__ pos,
                        float* __restrict__ t) {
  int idx = blockIdx.x * blockDim.x + threadIdx.x;
  if (idx >= BB * LL * CC) return;
  int c = idx % CC;
  int l = (idx / CC) % LL;
  int b = idx / (CC * LL);
  int ph = l / WW, pwc = l % WW;
  float acc = pb[c];
  for (int ci = 0; ci < 3; ci++)
    for (int kh = 0; kh < PSZ; kh++) {
      const float* xr = x + ((size_t)(b * 3 + ci) * IMGS + ph * PSZ + kh) * IMGS + pwc * PSZ;
      const float* wr = pw + ((size_t)(c * 3 + ci) * PSZ + kh) * PSZ;
      for (int kw = 0; kw < PSZ; kw++) acc += xr[kw] * wr[kw];
    }
  t[idx] = acc + pos[l * CC + c];
}

// ---------------- LayerNorm over C=96, one wave per token ----------------
__global__ void k_ln96(const float* __restrict__ in, const float* __restrict__ w,
                       const float* __restrict__ bias, float* __restrict__ out) {
  int tok = blockIdx.x;
  int lane = threadIdx.x;
  const float* p = in + (size_t)tok * CC;
  float v0 = p[lane];
  float v1 = (lane < CC - 64) ? p[lane + 64] : 0.f;
  float mu = wave_sum(v0 + v1) * (1.f / CC);
  float d0 = v0 - mu;
  float d1 = (lane < CC - 64) ? (v1 - mu) : 0.f;
  float var = wave_sum(d0 * d0 + d1 * d1) * (1.f / CC);
  float rs = rsqrtf(var + 1e-6f);
  out[(size_t)tok * CC + lane] = d0 * rs * w[lane] + bias[lane];
  if (lane < CC - 64)
    out[(size_t)tok * CC + lane + 64] = d1 * rs * w[lane + 64] + bias[lane + 64];
}

// ---------------- in_proj: (B,L,C) x (C,2D) -> xz (B,L,2D) ----------------
__global__ void k_inproj(const float* __restrict__ xln, const float* __restrict__ ipw,
                         float* __restrict__ xz) {
  int idx = blockIdx.x * blockDim.x + threadIdx.x;
  if (idx >= BB * LL * 2 * DD) return;
  int j = idx % (2 * DD);
  int tok = idx / (2 * DD);
  const float* p = xln + (size_t)tok * CC;
  float acc = 0.f;
  for (int c = 0; c < CC; c++) acc += p[c] * ipw[(size_t)c * (2 * DD) + j];
  xz[idx] = acc;
}

// ---------------- depthwise 3x3 SAME conv + bias + SiLU -> xc (B,D,L) ----------------
__global__ void k_conv(const float* __restrict__ xz, const float* __restrict__ cw,
                       const float* __restrict__ cb, float* __restrict__ xc) {
  int idx = blockIdx.x * blockDim.x + threadIdx.x;
  if (idx >= BB * DD * LL) return;
  int l = idx % LL;
  int d = (idx / LL) % DD;
  int b = idx / (LL * DD);
  int h = l / WW, w = l % WW;
  float acc = cb[d];
  for (int kh = 0; kh < 3; kh++) {
    int hh = h + kh - 1;
    if (hh < 0 || hh >= HH) continue;
    for (int kw = 0; kw < 3; kw++) {
      int ww = w + kw - 1;
      if (ww < 0 || ww >= WW) continue;
      acc += xz[((size_t)(b * LL + hh * WW + ww)) * (2 * DD) + d] * cw[d * 9 + kh * 3 + kw];
    }
  }
  xc[idx] = silu_f(acc);
}

// ---------------- x_proj: dbl[b,k,l,c] = sum_d xs[b,k,d,l] * xpw[k,c,d] ----------------
__global__ void k_xproj(const float* __restrict__ xc, const float* __restrict__ xpw,
                        float* __restrict__ dbl) {
  int idx = blockIdx.x * blockDim.x + threadIdx.x;
  if (idx >= BB * KDIR * LL * DBLC) return;
  int c = idx % DBLC;
  int l = (idx / DBLC) % LL;
  int k = (idx / (DBLC * LL)) % KDIR;
  int b = idx / (DBLC * LL * KDIR);
  int src = xs_src(k, l);
  const float* xcb = xc + (size_t)b * DD * LL + src;
  const float* wp = xpw + ((size_t)k * DBLC + c) * DD;
  float acc = 0.f;
  for (int d = 0; d < DD; d++) acc += xcb[(size_t)d * LL] * wp[d];
  dbl[idx] = acc;
}

// ---------------- selective scan v2: segmented, one WAVE per (b,k,d) chain ----------------
// wave = 4 groups of 16 lanes; group s handles segment s (49 steps); lane n = state.
// Pass 1: local scan from h=0, track decay product; cache dt/dtx/xv in LDS.
// Combine: h_in(s) = cum(s-1)*h_in(s-1) + hL(s-1) via 3 shuffle steps.
// Pass 2: re-scan from correct h_in, produce y, atomic-merge into ym at xs_src(k,l).
__global__ void k_scan(const float* __restrict__ xc, const float* __restrict__ dbl,
                       const float* __restrict__ dtw, const float* __restrict__ dtb,
                       const float* __restrict__ alog, const float* __restrict__ dsv,
                       float* __restrict__ ym) {
  __shared__ float s_dt[4][LL];
  __shared__ float s_dtx[4][LL];
  __shared__ float s_xv[4][LL];
  int wv = threadIdx.x >> 6;        // wave within block (0..3)
  int lane = threadIdx.x & 63;
  int s = lane >> 4;                // segment (0..3)
  int n = lane & 15;                // state
  int g = blockIdx.x * 4 + wv;      // chain id = (b*K + k)*D + d
  int d = g % DD;
  int k = (g / DD) % KDIR;
  int b = g / (DD * KDIR);

  float A = -expf(alog[((size_t)k * DD + d) * NSTATE + n]);
  float Dsc = dsv[k * DD + d];
  const float* wp = dtw + ((size_t)k * DD + d) * RRANK;
  float w0 = wp[0], w1 = wp[1], w2 = wp[2], w3 = wp[3], w4 = wp[4], w5 = wp[5];
  float dtbias = dtb[k * DD + d];
  const float* blp = dbl + (size_t)(b * KDIR + k) * LL * DBLC;
  const float* xcb = xc + (size_t)b * DD * LL + (size_t)d * LL;

  // ---- pass 1: local scan, h=0 start ----
  float h = 0.f, cum = 1.f;
  int l0 = s * SEG;
  for (int i = 0; i < SEG; i++) {
    int l = l0 + i;
    const float* q = blp + (size_t)l * DBLC;
    float dtl = dtbias + q[0] * w0 + q[1] * w1 + q[2] * w2 + q[3] * w3 + q[4] * w4 + q[5] * w5;
    dtl = softplus_f(dtl);
    float xv = xcb[xs_src(k, l)];
    float dtx = dtl * xv;
    if (n == 0) {
      s_dt[wv][l] = dtl;
      s_dtx[wv][l] = dtx;
      s_xv[wv][l] = xv;
    }
    float a = expf(dtl * A);
    h = h * a + dtx * q[6 + n];
    cum *= a;
  }

  // ---- combine across segments (in-wave) ----
  float Hact = h;        // becomes actual end-state of this segment
  float hin = 0.f;       // incoming state for this segment
#pragma unroll
  for (int step = 1; step <= 3; step++) {
    float Hprev = __shfl(Hact, n + (step - 1) * 16, 64);
    if (s == step) {
      hin = Hprev;
      Hact = cum * Hprev + Hact;
    }
  }

  __syncthreads();  // LDS dt/dtx/xv visible

  // ---- pass 2: exact scan from h_in, emit y ----
  float* yo = ym + (size_t)b * LL * DD;
  h = hin;
  for (int i = 0; i < SEG; i++) {
    int l = l0 + i;
    const float* q = blp + (size_t)l * DBLC;
    float dtl = s_dt[wv][l];
    float dtx = s_dtx[wv][l];
    float xv = s_xv[wv][l];
    float a = expf(dtl * A);
    h = h * a + dtx * q[6 + n];
    float part = h * q[22 + n];
    part += __shfl_xor(part, 1, 64);
    part += __shfl_xor(part, 2, 64);
    part += __shfl_xor(part, 4, 64);
    part += __shfl_xor(part, 8, 64);
    if (n == 0) atomicAdd(&yo[(size_t)xs_src(k, l) * DD + d], part + Dsc * xv);
  }
}

// ---------------- out_norm (LN over D=192) * silu(z) -> g (B,L,D); one wave/token ----------------
__global__ void k_lngate(const float* __restrict__ ym, const float* __restrict__ onw,
                         const float* __restrict__ onb, const float* __restrict__ xz,
                         float* __restrict__ g) {
  int tok = blockIdx.x;
  int lane = threadIdx.x;
  const float* p = ym + (size_t)tok * DD;
  float v0 = p[lane], v1 = p[lane + 64], v2 = p[lane + 128];
  float mu = wave_sum(v0 + v1 + v2) * (1.f / DD);
  float d0 = v0 - mu, d1 = v1 - mu, d2 = v2 - mu;
  float var = wave_sum(d0 * d0 + d1 * d1 + d2 * d2) * (1.f / DD);
  float rs = rsqrtf(var + 1e-6f);
  const float* zp = xz + (size_t)tok * 2 * DD + DD;
  float* go = g + (size_t)tok * DD;
  go[lane]       = (d0 * rs * onw[lane] + onb[lane]) * silu_f(zp[lane]);
  go[lane + 64]  = (d1 * rs * onw[lane + 64] + onb[lane + 64]) * silu_f(zp[lane + 64]);
  go[lane + 128] = (d2 * rs * onw[lane + 128] + onb[lane + 128]) * silu_f(zp[lane + 128]);
}

// ---------------- out_proj + residual: t[b,l,c] += sum_d g*opw ----------------
__global__ void k_outproj(const float* __restrict__ g, const float* __restrict__ opw,
                          float* __restrict__ t) {
  int idx = blockIdx.x * blockDim.x + threadIdx.x;
  if (idx >= BB * LL * CC) return;
  int c = idx % CC;
  int tok = idx / CC;
  const float* gp = g + (size_t)tok * DD;
  float acc = 0.f;
  for (int d = 0; d < DD; d++) acc += gp[d] * opw[(size_t)d * CC + c];
  t[idx] += acc;
}

// ---------------- final mean-pool over L ----------------
__global__ void k_pool(const float* __restrict__ tf, float* __restrict__ pooled) {
  int idx = blockIdx.x * blockDim.x + threadIdx.x;
  if (idx >= BB * CC) return;
  int c = idx % CC;
  int b = idx / CC;
  float acc = 0.f;
  for (int l = 0; l < LL; l++) acc += tf[((size_t)b * LL + l) * CC + c];
  pooled[idx] = acc * (1.f / LL);
}

// ---------------- head ----------------
__global__ void k_head(const float* __restrict__ pooled, const float* __restrict__ hw,
                       const float* __restrict__ hb, float* __restrict__ out) {
  int idx = blockIdx.x * blockDim.x + threadIdx.x;
  if (idx >= BB * NCLS) return;
  int j = idx % NCLS;
  int b = idx / NCLS;
  float acc = hb[j];
  for (int c = 0; c < CC; c++) acc += pooled[b * CC + c] * hw[c * NCLS + j];
  out[idx] = acc;
}

extern "C" void kernel_launch(void* const* d_in, const int* in_sizes, int n_in,
                              void* d_out, int out_size, void* d_ws, size_t ws_size,
                              hipStream_t stream) {
  const float* x       = (const float*)d_in[0];
  const float* patch_w = (const float*)d_in[1];
  const float* patch_b = (const float*)d_in[2];
  const float* pos     = (const float*)d_in[3];
  const float* ln1_w   = (const float*)d_in[4];
  const float* ln1_b   = (const float*)d_in[5];
  const float* ipw     = (const float*)d_in[6];
  const float* cw      = (const float*)d_in[7];
  const float* cb      = (const float*)d_in[8];
  const float* xpw     = (const float*)d_in[9];
  const float* dtw     = (const float*)d_in[10];
  const float* dtb     = (const float*)d_in[11];
  const float* alog    = (const float*)d_in[12];
  const float* dsp     = (const float*)d_in[13];
  const float* onw     = (const float*)d_in[14];
  const float* onb     = (const float*)d_in[15];
  const float* opw     = (const float*)d_in[16];
  const float* nw      = (const float*)d_in[17];
  const float* nb      = (const float*)d_in[18];
  const float* hw      = (const float*)d_in[19];
  const float* hb      = (const float*)d_in[20];
  float* out = (float*)d_out;

  // Workspace layout — total 1,743,616 floats = 6.97 MB
  float* wsf  = (float*)d_ws;
  float* t    = wsf;                           // B*L*C    = 150528
  float* xln  = t    + BB * LL * CC;           // 150528   (reused as tf at end)
  float* xz   = xln  + BB * LL * CC;           // B*L*2D   = 602112
  float* xc   = xz   + BB * LL * 2 * DD;       // B*D*L    = 301056  (reused as gbuf post-scan)
  float* dbl  = xc   + BB * DD * LL;           // B*K*L*38 = 238336  (reused as pooled at end)
  float* ym   = dbl  + BB * KDIR * LL * DBLC;  // B*L*D    = 301056
  float* gbuf = xc;                            // alias: xc dead after scan
  float* tf   = xln;                           // alias: xln dead after last layer
  float* pooled = dbl;                         // alias: dbl dead after last layer

  k_patch<<<(BB * LL * CC + 255) / 256, 256, 0, stream>>>(x, patch_w, patch_b, pos, t);

  for (int i = 0; i < DEPTH; i++) {
    k_ln96<<<BB * LL, 64, 0, stream>>>(t, ln1_w + i * CC, ln1_b + i * CC, xln);
    k_inproj<<<(BB * LL * 2 * DD + 255) / 256, 256, 0, stream>>>(
        xln, ipw + (size_t)i * CC * 2 * DD, xz);
    k_conv<<<(BB * DD * LL + 255) / 256, 256, 0, stream>>>(xz, cw + i * DD * 9, cb + i * DD, xc);
    k_xproj<<<(BB * KDIR * LL * DBLC + 255) / 256, 256, 0, stream>>>(
        xc, xpw + (size_t)i * KDIR * DBLC * DD, dbl);
    hipMemsetAsync(ym, 0, (size_t)BB * LL * DD * sizeof(float), stream);
    // one wave per chain, 4 chains per block: 6144 chains / 4 = 1536 blocks
    k_scan<<<BB * KDIR * DD / 4, 256, 0, stream>>>(
        xc, dbl, dtw + (size_t)i * KDIR * DD * RRANK, dtb + i * KDIR * DD,
        alog + (size_t)i * KDIR * DD * NSTATE, dsp + i * KDIR * DD, ym);
    k_lngate<<<BB * LL, 64, 0, stream>>>(ym, onw + i * DD, onb + i * DD, xz, gbuf);
    k_outproj<<<(BB * LL * CC + 255) / 256, 256, 0, stream>>>(gbuf, opw + (size_t)i * DD * CC, t);
  }

  k_ln96<<<BB * LL, 64, 0, stream>>>(t, nw, nb, tf);
  k_pool<<<(BB * CC + 255) / 256, 256, 0, stream>>>(tf, pooled);
  k_head<<<(BB * NCLS + 255) / 256, 256, 0, stream>>>(pooled, hw, hb, out);
}

// Round 4
// 2108.082 us; speedup vs baseline: 1.7848x; 1.4082x over previous
//
#include <hip/hip_runtime.h>
#include <math.h>

#define BB 8
#define IMGS 224
#define PSZ 16
#define CC 96
#define DEPTH 12
#define NCLS 43
#define HH 14
#define WW 14
#define LL 196
#define DD 192
#define NSTATE 16
#define RRANK 6
#define KDIR 4
#define DBLC 38   // R + 2N = 6 + 32 (logical)
#define DBLP 40   // padded row: dt[0..5], pad[6..7], B[8..23], C[24..39]; 160B aligned
#define SEG 49    // L / 4 segments per chain
#define PTOK 4    // tokens per patch-embed block

__device__ __forceinline__ float wave_sum(float v) {
#pragma unroll
  for (int m = 32; m; m >>= 1) v += __shfl_xor(v, m, 64);
  return v;
}

__device__ __forceinline__ float silu_f(float x) {
  return x / (1.f + __expf(-x));
}

// ---------------- patch embed: 4 tokens/block, LDS-staged patch, contiguous weight reads ----------------
__global__ void k_patch(const float* __restrict__ x, const float* __restrict__ pw,
                        const float* __restrict__ pb, const float* __restrict__ pos,
                        float* __restrict__ t) {
  __shared__ float s_x[PTOK][768];  // 3*16*16 per token
  int tok0 = blockIdx.x * PTOK;
  for (int tk = 0; tk < PTOK; tk++) {
    int tok = tok0 + tk;
    int b = tok / LL, l = tok % LL;
    int ph = l / WW, pwc = l % WW;
    for (int e = threadIdx.x; e < 768; e += 128) {
      int ci = e >> 8, kh = (e >> 4) & 15, kw = e & 15;
      s_x[tk][e] = x[((size_t)(b * 3 + ci) * IMGS + ph * PSZ + kh) * IMGS + pwc * PSZ + kw];
    }
  }
  __syncthreads();
  if (threadIdx.x < CC) {
    int c = threadIdx.x;
    float a0 = pb[c], a1 = a0, a2 = a0, a3 = a0;
    const float* wr = pw + (size_t)c * 768;
    for (int e = 0; e < 768; e++) {
      float wv = wr[e];
      a0 += s_x[0][e] * wv;
      a1 += s_x[1][e] * wv;
      a2 += s_x[2][e] * wv;
      a3 += s_x[3][e] * wv;
    }
    float acc[4] = {a0, a1, a2, a3};
    for (int tk = 0; tk < PTOK; tk++) {
      int tok = tok0 + tk;
      t[(size_t)tok * CC + c] = acc[tk] + pos[(tok % LL) * CC + c];
    }
  }
}

// ---------------- fused LN(96) + in_proj -> xz (B,L,2D); one block (384 thr) per token ----------------
__global__ void k_lnproj(const float* __restrict__ t, const float* __restrict__ w,
                         const float* __restrict__ bias, const float* __restrict__ ipw,
                         float* __restrict__ xz) {
  __shared__ float s_x[CC];
  int tok = blockIdx.x;
  if (threadIdx.x < 64) {
    int lane = threadIdx.x;
    const float* p = t + (size_t)tok * CC;
    float v0 = p[lane];
    float v1 = (lane < CC - 64) ? p[lane + 64] : 0.f;
    float mu = wave_sum(v0 + v1) * (1.f / CC);
    float d0 = v0 - mu;
    float d1 = (lane < CC - 64) ? (v1 - mu) : 0.f;
    float var = wave_sum(d0 * d0 + d1 * d1) * (1.f / CC);
    float rs = rsqrtf(var + 1e-6f);
    s_x[lane] = d0 * rs * w[lane] + bias[lane];
    if (lane < CC - 64) s_x[lane + 64] = d1 * rs * w[lane + 64] + bias[lane + 64];
  }
  __syncthreads();
  int j = threadIdx.x;  // 0..383
  float acc = 0.f;
  for (int c = 0; c < CC; c++) acc += s_x[c] * ipw[(size_t)c * (2 * DD) + j];
  xz[(size_t)tok * (2 * DD) + j] = acc;
}

// ---------------- depthwise 3x3 + bias + SiLU -> xcT (B,L,D); d-fastest, fully coalesced ----------------
__global__ void k_conv(const float* __restrict__ xz, const float* __restrict__ cw,
                       const float* __restrict__ cb, float* __restrict__ xcT) {
  int idx = blockIdx.x * blockDim.x + threadIdx.x;
  if (idx >= BB * LL * DD) return;
  int d = idx % DD;
  int rem = idx / DD;
  int l = rem % LL;
  int b = rem / LL;
  int h = l / WW, w = l % WW;
  float acc = cb[d];
  for (int kh = 0; kh < 3; kh++) {
    int hh = h + kh - 1;
    if (hh < 0 || hh >= HH) continue;
    for (int kw = 0; kw < 3; kw++) {
      int ww = w + kw - 1;
      if (ww < 0 || ww >= WW) continue;
      acc += xz[((size_t)(b * LL + hh * WW + ww)) * (2 * DD) + d] * cw[d * 9 + kh * 3 + kw];
    }
  }
  xcT[((size_t)(b * LL) + l) * DD + d] = silu_f(acc);
}

// ---------------- x_proj: dbl[b,k,l,sc] = sum_d xcT[b,src,d] * xpw[k,c,d]; padded row ----------------
__global__ void k_xproj(const float* __restrict__ xcT, const float* __restrict__ xpw,
                        float* __restrict__ dbl) {
  int idx = blockIdx.x * blockDim.x + threadIdx.x;
  if (idx >= BB * KDIR * LL * DBLC) return;
  int c = idx % DBLC;
  int l = (idx / DBLC) % LL;
  int k = (idx / (DBLC * LL)) % KDIR;
  int b = idx / (DBLC * LL * KDIR);
  int lr = (k >= 2) ? (LL - 1 - l) : l;
  int src = (k & 1) ? ((lr % HH) * WW + lr / HH) : lr;
  const float* xr = xcT + ((size_t)b * LL + src) * DD;
  const float* wp = xpw + ((size_t)k * DBLC + c) * DD;
  float acc = 0.f;
  for (int d = 0; d < DD; d++) acc += xr[d] * wp[d];
  int sc = (c < RRANK) ? c : c + 2;
  dbl[(((size_t)(b * KDIR + k)) * LL + l) * DBLP + sc] = acc;
}

// ---------------- selective scan: segmented, one wave per (b,k,d) chain; fast exp/log ----------------
__global__ void k_scan(const float* __restrict__ xcT, const float* __restrict__ dbl,
                       const float* __restrict__ dtw, const float* __restrict__ dtb,
                       const float* __restrict__ alog, const float* __restrict__ dsv,
                       float* __restrict__ ym) {
  __shared__ float s_dt[4][LL];
  __shared__ float s_dtx[4][LL];
  __shared__ float s_xv[4][LL];
  int wv = threadIdx.x >> 6;
  int lane = threadIdx.x & 63;
  int s = lane >> 4;
  int n = lane & 15;
  int g = blockIdx.x * 4 + wv;  // (b*K + k)*D + d ; 4 consecutive g share k (4 | D)
  int d = g % DD;
  int k = (g / DD) % KDIR;
  int b = g / (DD * KDIR);

  float A = -__expf(alog[((size_t)k * DD + d) * NSTATE + n]);
  float Dsc = dsv[k * DD + d];
  const float* wp = dtw + ((size_t)k * DD + d) * RRANK;
  float w0 = wp[0], w1 = wp[1], w2 = wp[2], w3 = wp[3], w4 = wp[4], w5 = wp[5];
  float dtbias = dtb[k * DD + d];
  const float* blp = dbl + (size_t)(b * KDIR + k) * LL * DBLP;
  const float* xcb = xcT + (size_t)b * LL * DD + d;

  int l0 = s * SEG;
  int dstep = (k >= 2) ? -1 : 1;
  bool tr = (k & 1);
  int lr = (k >= 2) ? (LL - 1 - l0) : l0;
  int qq = lr / WW;
  int rr = lr - qq * WW;

  // ---- pass 1: local scan from h=0 ----
  float h = 0.f, cum = 1.f;
  for (int i = 0; i < SEG; i++) {
    int l = l0 + i;
    int src = tr ? (rr * WW + qq) : lr;
    const float* q = blp + (size_t)l * DBLP;
    float4 q03 = *(const float4*)q;
    float2 q45 = *(const float2*)(q + 4);
    float m = dtbias + q03.x * w0 + q03.y * w1 + q03.z * w2 + q03.w * w3 + q45.x * w4 + q45.y * w5;
    float dtl = (m > 20.f) ? m : __logf(1.f + __expf(m));
    float xv = xcb[(size_t)src * DD];
    float dtx = dtl * xv;
    if (n == 0) {
      s_dt[wv][l] = dtl;
      s_dtx[wv][l] = dtx;
      s_xv[wv][l] = xv;
    }
    float a = __expf(dtl * A);
    h = h * a + dtx * q[8 + n];
    cum *= a;
    lr += dstep;
    rr += dstep;
    if (rr >= WW) { rr = 0; qq++; }
    else if (rr < 0) { rr = WW - 1; qq--; }
  }

  // ---- combine across segments (in-wave) ----
  float Hact = h;
  float hin = 0.f;
#pragma unroll
  for (int step = 1; step <= 3; step++) {
    float Hprev = __shfl(Hact, n + (step - 1) * 16, 64);
    if (s == step) {
      hin = Hprev;
      Hact = cum * Hprev + Hact;
    }
  }

  __syncthreads();

  // ---- pass 2: exact scan from h_in, emit y via atomic merge ----
  lr = (k >= 2) ? (LL - 1 - l0) : l0;
  qq = lr / WW;
  rr = lr - qq * WW;
  float* yo = ym + (size_t)b * LL * DD;
  h = hin;
  for (int i = 0; i < SEG; i++) {
    int l = l0 + i;
    int src = tr ? (rr * WW + qq) : lr;
    const float* q = blp + (size_t)l * DBLP;
    float dtl = s_dt[wv][l];
    float dtx = s_dtx[wv][l];
    float a = __expf(dtl * A);
    h = h * a + dtx * q[8 + n];
    float part = h * q[24 + n];
    part += __shfl_xor(part, 1, 64);
    part += __shfl_xor(part, 2, 64);
    part += __shfl_xor(part, 4, 64);
    part += __shfl_xor(part, 8, 64);
    if (n == 0) atomicAdd(&yo[(size_t)src * DD + d], part + Dsc * s_xv[wv][l]);
    lr += dstep;
    rr += dstep;
    if (rr >= WW) { rr = 0; qq++; }
    else if (rr < 0) { rr = WW - 1; qq--; }
  }
}

// ---------------- fused out_norm(192)*silu(z) + out_proj + residual; one block (192 thr)/token ----------------
__global__ void k_lngateout(const float* __restrict__ ym, const float* __restrict__ onw,
                            const float* __restrict__ onb, const float* __restrict__ xz,
                            const float* __restrict__ opw, float* __restrict__ t) {
  __shared__ float s_g[DD];
  __shared__ float s_r[3];
  int tok = blockIdx.x;
  int tid = threadIdx.x;
  int wv = tid >> 6;
  float v = ym[(size_t)tok * DD + tid];
  float p1 = wave_sum(v);
  if ((tid & 63) == 0) s_r[wv] = p1;
  __syncthreads();
  float mu = (s_r[0] + s_r[1] + s_r[2]) * (1.f / DD);
  __syncthreads();
  float dv = v - mu;
  float p2 = wave_sum(dv * dv);
  if ((tid & 63) == 0) s_r[wv] = p2;
  __syncthreads();
  float var = (s_r[0] + s_r[1] + s_r[2]) * (1.f / DD);
  float rs = rsqrtf(var + 1e-6f);
  float zz = xz[(size_t)tok * (2 * DD) + DD + tid];
  s_g[tid] = (dv * rs * onw[tid] + onb[tid]) * silu_f(zz);
  __syncthreads();
  if (tid < CC) {
    float acc = 0.f;
    for (int d = 0; d < DD; d++) acc += s_g[d] * opw[(size_t)d * CC + tid];
    t[(size_t)tok * CC + tid] += acc;
  }
}

// ---------------- fused final LN + mean-pool + head; one block (256 thr) per batch ----------------
__global__ void k_final(const float* __restrict__ t, const float* __restrict__ nw,
                        const float* __restrict__ nb, const float* __restrict__ hw,
                        const float* __restrict__ hb, float* __restrict__ out) {
  __shared__ float s_acc[4][CC];
  __shared__ float s_pool[CC];
  int b = blockIdx.x;
  int wv = threadIdx.x >> 6;
  int lane = threadIdx.x & 63;
  float accA = 0.f, accB = 0.f;
  for (int i = 0; i < SEG; i++) {
    int l = wv * SEG + i;
    const float* p = t + ((size_t)b * LL + l) * CC;
    float v0 = p[lane];
    float v1 = (lane < CC - 64) ? p[lane + 64] : 0.f;
    float mu = wave_sum(v0 + v1) * (1.f / CC);
    float d0 = v0 - mu;
    float d1 = (lane < CC - 64) ? (v1 - mu) : 0.f;
    float var = wave_sum(d0 * d0 + d1 * d1) * (1.f / CC);
    float rs = rsqrtf(var + 1e-6f);
    accA += d0 * rs * nw[lane] + nb[lane];
    if (lane < CC - 64) accB += d1 * rs * nw[lane + 64] + nb[lane + 64];
  }
  s_acc[wv][lane] = accA;
  if (lane < CC - 64) s_acc[wv][lane + 64] = accB;
  __syncthreads();
  if (threadIdx.x < CC)
    s_pool[threadIdx.x] = (s_acc[0][threadIdx.x] + s_acc[1][threadIdx.x] +
                           s_acc[2][threadIdx.x] + s_acc[3][threadIdx.x]) * (1.f / LL);
  __syncthreads();
  if (threadIdx.x < NCLS) {
    int j = threadIdx.x;
    float acc = hb[j];
    for (int c = 0; c < CC; c++) acc += s_pool[c] * hw[c * NCLS + j];
    out[b * NCLS + j] = acc;
  }
}

extern "C" void kernel_launch(void* const* d_in, const int* in_sizes, int n_in,
                              void* d_out, int out_size, void* d_ws, size_t ws_size,
                              hipStream_t stream) {
  const float* x       = (const float*)d_in[0];
  const float* patch_w = (const float*)d_in[1];
  const float* patch_b = (const float*)d_in[2];
  const float* pos     = (const float*)d_in[3];
  const float* ln1_w   = (const float*)d_in[4];
  const float* ln1_b   = (const float*)d_in[5];
  const float* ipw     = (const float*)d_in[6];
  const float* cw      = (const float*)d_in[7];
  const float* cb      = (const float*)d_in[8];
  const float* xpw     = (const float*)d_in[9];
  const float* dtw     = (const float*)d_in[10];
  const float* dtb     = (const float*)d_in[11];
  const float* alog    = (const float*)d_in[12];
  const float* dsp     = (const float*)d_in[13];
  const float* onw     = (const float*)d_in[14];
  const float* onb     = (const float*)d_in[15];
  const float* opw     = (const float*)d_in[16];
  const float* nw      = (const float*)d_in[17];
  const float* nb      = (const float*)d_in[18];
  const float* hw      = (const float*)d_in[19];
  const float* hb      = (const float*)d_in[20];
  float* out = (float*)d_out;

  // Workspace: 1,605,632 floats = 6.42 MB
  float* wsf = (float*)d_ws;
  float* t   = wsf;                          // B*L*C    = 150528
  float* xz  = t   + BB * LL * CC;           // B*L*2D   = 602112
  float* xcT = xz  + BB * LL * 2 * DD;       // B*L*D    = 301056
  float* dbl = xcT + BB * LL * DD;           // B*K*L*40 = 250880
  float* ym  = dbl + BB * KDIR * LL * DBLP;  // B*L*D    = 301056

  k_patch<<<BB * LL / PTOK, 128, 0, stream>>>(x, patch_w, patch_b, pos, t);

  for (int i = 0; i < DEPTH; i++) {
    k_lnproj<<<BB * LL, 384, 0, stream>>>(t, ln1_w + i * CC, ln1_b + i * CC,
                                          ipw + (size_t)i * CC * 2 * DD, xz);
    k_conv<<<(BB * LL * DD + 255) / 256, 256, 0, stream>>>(xz, cw + i * DD * 9, cb + i * DD, xcT);
    k_xproj<<<(BB * KDIR * LL * DBLC + 255) / 256, 256, 0, stream>>>(
        xcT, xpw + (size_t)i * KDIR * DBLC * DD, dbl);
    hipMemsetAsync(ym, 0, (size_t)BB * LL * DD * sizeof(float), stream);
    k_scan<<<BB * KDIR * DD / 4, 256, 0, stream>>>(
        xcT, dbl, dtw + (size_t)i * KDIR * DD * RRANK, dtb + i * KDIR * DD,
        alog + (size_t)i * KDIR * DD * NSTATE, dsp + i * KDIR * DD, ym);
    k_lngateout<<<BB * LL, DD, 0, stream>>>(ym, onw + i * DD, onb + i * DD, xz,
                                            opw + (size_t)i * DD * CC, t);
  }

  k_final<<<BB, 256, 0, stream>>>(t, nw, nb, hw, hb, out);
}

// Round 5
// 1871.939 us; speedup vs baseline: 2.0099x; 1.1261x over previous
//
#include <hip/hip_runtime.h>
#include <math.h>

#define BB 8
#define IMGS 224
#define PSZ 16
#define CC 96
#define DEPTH 12
#define NCLS 43
#define HH 14
#define WW 14
#define LL 196
#define DD 192
#define NSTATE 16
#define RRANK 6
#define KDIR 4
#define DBLC 38   // R + 2N = 6 + 32 (logical)
#define DBLP 40   // padded row: dt[0..5], pad[6..7], B[8..23], C[24..39]; 160B aligned
#define NSEG 16   // segments per chain (16-lane group each)
#define PTOK 4    // tokens per patch-embed block

__device__ __forceinline__ float wave_sum(float v) {
#pragma unroll
  for (int m = 32; m; m >>= 1) v += __shfl_xor(v, m, 64);
  return v;
}

__device__ __forceinline__ float silu_f(float x) {
  return x / (1.f + __expf(-x));
}

// ---------------- patch embed: 4 tokens/block, LDS-staged patch, contiguous weight reads ----------------
__global__ void k_patch(const float* __restrict__ x, const float* __restrict__ pw,
                        const float* __restrict__ pb, const float* __restrict__ pos,
                        float* __restrict__ t) {
  __shared__ float s_x[PTOK][768];  // 3*16*16 per token
  int tok0 = blockIdx.x * PTOK;
  for (int tk = 0; tk < PTOK; tk++) {
    int tok = tok0 + tk;
    int b = tok / LL, l = tok % LL;
    int ph = l / WW, pwc = l % WW;
    for (int e = threadIdx.x; e < 768; e += 128) {
      int ci = e >> 8, kh = (e >> 4) & 15, kw = e & 15;
      s_x[tk][e] = x[((size_t)(b * 3 + ci) * IMGS + ph * PSZ + kh) * IMGS + pwc * PSZ + kw];
    }
  }
  __syncthreads();
  if (threadIdx.x < CC) {
    int c = threadIdx.x;
    float a0 = pb[c], a1 = a0, a2 = a0, a3 = a0;
    const float* wr = pw + (size_t)c * 768;
    for (int e = 0; e < 768; e++) {
      float wv = wr[e];
      a0 += s_x[0][e] * wv;
      a1 += s_x[1][e] * wv;
      a2 += s_x[2][e] * wv;
      a3 += s_x[3][e] * wv;
    }
    float acc[4] = {a0, a1, a2, a3};
    for (int tk = 0; tk < PTOK; tk++) {
      int tok = tok0 + tk;
      t[(size_t)tok * CC + c] = acc[tk] + pos[(tok % LL) * CC + c];
    }
  }
}

// ---------------- fused LN(96) + in_proj -> xz (B,L,2D); one block (384 thr) per token ----------------
__global__ void k_lnproj(const float* __restrict__ t, const float* __restrict__ w,
                         const float* __restrict__ bias, const float* __restrict__ ipw,
                         float* __restrict__ xz) {
  __shared__ float s_x[CC];
  int tok = blockIdx.x;
  if (threadIdx.x < 64) {
    int lane = threadIdx.x;
    const float* p = t + (size_t)tok * CC;
    float v0 = p[lane];
    float v1 = (lane < CC - 64) ? p[lane + 64] : 0.f;
    float mu = wave_sum(v0 + v1) * (1.f / CC);
    float d0 = v0 - mu;
    float d1 = (lane < CC - 64) ? (v1 - mu) : 0.f;
    float var = wave_sum(d0 * d0 + d1 * d1) * (1.f / CC);
    float rs = rsqrtf(var + 1e-6f);
    s_x[lane] = d0 * rs * w[lane] + bias[lane];
    if (lane < CC - 64) s_x[lane + 64] = d1 * rs * w[lane + 64] + bias[lane + 64];
  }
  __syncthreads();
  int j = threadIdx.x;  // 0..383
  float acc = 0.f;
  for (int c = 0; c < CC; c++) acc += s_x[c] * ipw[(size_t)c * (2 * DD) + j];
  xz[(size_t)tok * (2 * DD) + j] = acc;
}

// ---------------- depthwise 3x3 + bias + SiLU -> xcT (B,L,D); d-fastest, fully coalesced ----------------
__global__ void k_conv(const float* __restrict__ xz, const float* __restrict__ cw,
                       const float* __restrict__ cb, float* __restrict__ xcT) {
  int idx = blockIdx.x * blockDim.x + threadIdx.x;
  if (idx >= BB * LL * DD) return;
  int d = idx % DD;
  int rem = idx / DD;
  int l = rem % LL;
  int b = rem / LL;
  int h = l / WW, w = l % WW;
  float acc = cb[d];
  for (int kh = 0; kh < 3; kh++) {
    int hh = h + kh - 1;
    if (hh < 0 || hh >= HH) continue;
    for (int kw = 0; kw < 3; kw++) {
      int ww = w + kw - 1;
      if (ww < 0 || ww >= WW) continue;
      acc += xz[((size_t)(b * LL + hh * WW + ww)) * (2 * DD) + d] * cw[d * 9 + kh * 3 + kw];
    }
  }
  xcT[((size_t)(b * LL) + l) * DD + d] = silu_f(acc);
}

// ---------------- x_proj: dbl[b,k,l,sc] = sum_d xcT[b,src,d] * xpw[k,c,d]; padded row ----------------
__global__ void k_xproj(const float* __restrict__ xcT, const float* __restrict__ xpw,
                        float* __restrict__ dbl) {
  int idx = blockIdx.x * blockDim.x + threadIdx.x;
  if (idx >= BB * KDIR * LL * DBLC) return;
  int c = idx % DBLC;
  int l = (idx / DBLC) % LL;
  int k = (idx / (DBLC * LL)) % KDIR;
  int b = idx / (DBLC * LL * KDIR);
  int lr = (k >= 2) ? (LL - 1 - l) : l;
  int src = (k & 1) ? ((lr % HH) * WW + lr / HH) : lr;
  const float* xr = xcT + ((size_t)b * LL + src) * DD;
  const float* wp = xpw + ((size_t)k * DBLC + c) * DD;
  float acc = 0.f;
  for (int d = 0; d < DD; d++) acc += xr[d] * wp[d];
  int sc = (c < RRANK) ? c : c + 2;
  dbl[(((size_t)(b * KDIR + k)) * LL + l) * DBLP + sc] = acc;
}

// ---------------- selective scan v3: one BLOCK per (b,k,d) chain, 16 segments ----------------
// Group s (16 lanes, lane n = state) scans segment s (12-13 steps).
// Pass 1: local scan from h=0; computes y_local = C.h_local + Ds*x (full global loads);
//         caches dt (for decay recompute) and C in LDS; tracks cum = prod(a).
// Combine: 16-step serial prefix by 16 threads -> h_in per segment.
// Pass 2 (pure LDS+VALU): P *= a; y = y_local + (P*h_in).C ; atomic merge into ym.
__global__ __launch_bounds__(256, 8) void k_scan(
    const float* __restrict__ xcT, const float* __restrict__ dbl,
    const float* __restrict__ dtw, const float* __restrict__ dtb,
    const float* __restrict__ alog, const float* __restrict__ dsv,
    float* __restrict__ ym) {
  __shared__ float s_dt[LL];
  __shared__ float s_y[LL];
  __shared__ float s_C[LL][NSTATE];
  __shared__ float s_cum[NSEG][NSTATE];
  __shared__ float s_hend[NSEG][NSTATE];
  __shared__ float s_hin[NSEG][NSTATE];
  int tid = threadIdx.x;
  int s = tid >> 4;   // segment 0..15
  int n = tid & 15;   // state
  int g = blockIdx.x; // (b*K + k)*D + d
  int d = g % DD;
  int k = (g / DD) % KDIR;
  int b = g / (DD * KDIR);

  float A = -__expf(alog[((size_t)k * DD + d) * NSTATE + n]);
  float Dsc = dsv[k * DD + d];
  const float* wp = dtw + ((size_t)k * DD + d) * RRANK;
  float w0 = wp[0], w1 = wp[1], w2 = wp[2], w3 = wp[3], w4 = wp[4], w5 = wp[5];
  float dtbias = dtb[k * DD + d];
  const float* blp = dbl + (size_t)(b * KDIR + k) * LL * DBLP;
  const float* xcb = xcT + (size_t)b * LL * DD + d;

  // segment extents: first 4 segments have 13 steps, rest 12 (4*13 + 12*12 = 196)
  int len = (s < 4) ? 13 : 12;
  int l0 = s * 12 + ((s < 4) ? s : 4);
  int dstep = (k >= 2) ? -1 : 1;
  bool tr = (k & 1);
  int lr = (k >= 2) ? (LL - 1 - l0) : l0;
  int qq = lr / WW;
  int rr = lr - qq * WW;

  // ---- pass 1: local scan from h=0; emit y_local; cache dt, C ----
  float h = 0.f, cum = 1.f;
  for (int i = 0; i < len; i++) {
    int l = l0 + i;
    const float* q = blp + (size_t)l * DBLP;
    float4 q03 = *(const float4*)q;
    float2 q45 = *(const float2*)(q + 4);
    float m = dtbias + q03.x * w0 + q03.y * w1 + q03.z * w2 + q03.w * w3 + q45.x * w4 + q45.y * w5;
    float dtl = (m > 20.f) ? m : __logf(1.f + __expf(m));
    int src = tr ? (rr * WW + qq) : lr;
    float xv = xcb[(size_t)src * DD];
    float a = __expf(dtl * A);
    h = h * a + (dtl * xv) * q[8 + n];
    cum *= a;
    float Cn = q[24 + n];
    s_C[l][n] = Cn;
    float part = h * Cn;
    part += __shfl_xor(part, 1, 64);
    part += __shfl_xor(part, 2, 64);
    part += __shfl_xor(part, 4, 64);
    part += __shfl_xor(part, 8, 64);
    if (n == 0) {
      s_dt[l] = dtl;
      s_y[l] = part + Dsc * xv;
    }
    lr += dstep;
    rr += dstep;
    if (rr >= WW) { rr = 0; qq++; }
    else if (rr < 0) { rr = WW - 1; qq--; }
  }
  s_cum[s][n] = cum;
  s_hend[s][n] = h;
  __syncthreads();

  // ---- combine: serial 16-step prefix per state (16 threads) ----
  if (tid < NSTATE) {
    float hh = 0.f;
    for (int ss = 0; ss < NSEG; ss++) {
      s_hin[ss][tid] = hh;
      hh = s_cum[ss][tid] * hh + s_hend[ss][tid];
    }
  }
  __syncthreads();

  // ---- pass 2: correction y += (P * h_in) . C ; atomic merge ----
  float hin = s_hin[s][n];
  lr = (k >= 2) ? (LL - 1 - l0) : l0;
  qq = lr / WW;
  rr = lr - qq * WW;
  float P = 1.f;
  float* yo = ym + (size_t)b * LL * DD;
  for (int i = 0; i < len; i++) {
    int l = l0 + i;
    int src = tr ? (rr * WW + qq) : lr;
    float a = __expf(s_dt[l] * A);
    P *= a;
    float part = P * hin * s_C[l][n];
    part += __shfl_xor(part, 1, 64);
    part += __shfl_xor(part, 2, 64);
    part += __shfl_xor(part, 4, 64);
    part += __shfl_xor(part, 8, 64);
    if (n == 0) atomicAdd(&yo[(size_t)src * DD + d], part + s_y[l]);
    lr += dstep;
    rr += dstep;
    if (rr >= WW) { rr = 0; qq++; }
    else if (rr < 0) { rr = WW - 1; qq--; }
  }
}

// ---------------- fused out_norm(192)*silu(z) + out_proj + residual; one block (192 thr)/token ----------------
__global__ void k_lngateout(const float* __restrict__ ym, const float* __restrict__ onw,
                            const float* __restrict__ onb, const float* __restrict__ xz,
                            const float* __restrict__ opw, float* __restrict__ t) {
  __shared__ float s_g[DD];
  __shared__ float s_r[3];
  int tok = blockIdx.x;
  int tid = threadIdx.x;
  int wv = tid >> 6;
  float v = ym[(size_t)tok * DD + tid];
  float p1 = wave_sum(v);
  if ((tid & 63) == 0) s_r[wv] = p1;
  __syncthreads();
  float mu = (s_r[0] + s_r[1] + s_r[2]) * (1.f / DD);
  __syncthreads();
  float dv = v - mu;
  float p2 = wave_sum(dv * dv);
  if ((tid & 63) == 0) s_r[wv] = p2;
  __syncthreads();
  float var = (s_r[0] + s_r[1] + s_r[2]) * (1.f / DD);
  float rs = rsqrtf(var + 1e-6f);
  float zz = xz[(size_t)tok * (2 * DD) + DD + tid];
  s_g[tid] = (dv * rs * onw[tid] + onb[tid]) * silu_f(zz);
  __syncthreads();
  if (tid < CC) {
    float acc = 0.f;
    for (int d = 0; d < DD; d++) acc += s_g[d] * opw[(size_t)d * CC + tid];
    t[(size_t)tok * CC + tid] += acc;
  }
}

// ---------------- fused final LN + mean-pool + head; one block (256 thr) per batch ----------------
__global__ void k_final(const float* __restrict__ t, const float* __restrict__ nw,
                        const float* __restrict__ nb, const float* __restrict__ hw,
                        const float* __restrict__ hb, float* __restrict__ out) {
  __shared__ float s_acc[4][CC];
  __shared__ float s_pool[CC];
  int b = blockIdx.x;
  int wv = threadIdx.x >> 6;
  int lane = threadIdx.x & 63;
  float accA = 0.f, accB = 0.f;
  for (int i = 0; i < 49; i++) {
    int l = wv * 49 + i;
    const float* p = t + ((size_t)b * LL + l) * CC;
    float v0 = p[lane];
    float v1 = (lane < CC - 64) ? p[lane + 64] : 0.f;
    float mu = wave_sum(v0 + v1) * (1.f / CC);
    float d0 = v0 - mu;
    float d1 = (lane < CC - 64) ? (v1 - mu) : 0.f;
    float var = wave_sum(d0 * d0 + d1 * d1) * (1.f / CC);
    float rs = rsqrtf(var + 1e-6f);
    accA += d0 * rs * nw[lane] + nb[lane];
    if (lane < CC - 64) accB += d1 * rs * nw[lane + 64] + nb[lane + 64];
  }
  s_acc[wv][lane] = accA;
  if (lane < CC - 64) s_acc[wv][lane + 64] = accB;
  __syncthreads();
  if (threadIdx.x < CC)
    s_pool[threadIdx.x] = (s_acc[0][threadIdx.x] + s_acc[1][threadIdx.x] +
                           s_acc[2][threadIdx.x] + s_acc[3][threadIdx.x]) * (1.f / LL);
  __syncthreads();
  if (threadIdx.x < NCLS) {
    int j = threadIdx.x;
    float acc = hb[j];
    for (int c = 0; c < CC; c++) acc += s_pool[c] * hw[c * NCLS + j];
    out[b * NCLS + j] = acc;
  }
}

extern "C" void kernel_launch(void* const* d_in, const int* in_sizes, int n_in,
                              void* d_out, int out_size, void* d_ws, size_t ws_size,
                              hipStream_t stream) {
  const float* x       = (const float*)d_in[0];
  const float* patch_w = (const float*)d_in[1];
  const float* patch_b = (const float*)d_in[2];
  const float* pos     = (const float*)d_in[3];
  const float* ln1_w   = (const float*)d_in[4];
  const float* ln1_b   = (const float*)d_in[5];
  const float* ipw     = (const float*)d_in[6];
  const float* cw      = (const float*)d_in[7];
  const float* cb      = (const float*)d_in[8];
  const float* xpw     = (const float*)d_in[9];
  const float* dtw     = (const float*)d_in[10];
  const float* dtb     = (const float*)d_in[11];
  const float* alog    = (const float*)d_in[12];
  const float* dsp     = (const float*)d_in[13];
  const float* onw     = (const float*)d_in[14];
  const float* onb     = (const float*)d_in[15];
  const float* opw     = (const float*)d_in[16];
  const float* nw      = (const float*)d_in[17];
  const float* nb      = (const float*)d_in[18];
  const float* hw      = (const float*)d_in[19];
  const float* hb      = (const float*)d_in[20];
  float* out = (float*)d_out;

  // Workspace: 1,605,632 floats = 6.42 MB
  float* wsf = (float*)d_ws;
  float* t   = wsf;                          // B*L*C    = 150528
  float* xz  = t   + BB * LL * CC;           // B*L*2D   = 602112
  float* xcT = xz  + BB * LL * 2 * DD;       // B*L*D    = 301056
  float* dbl = xcT + BB * LL * DD;           // B*K*L*40 = 250880
  float* ym  = dbl + BB * KDIR * LL * DBLP;  // B*L*D    = 301056

  k_patch<<<BB * LL / PTOK, 128, 0, stream>>>(x, patch_w, patch_b, pos, t);

  for (int i = 0; i < DEPTH; i++) {
    k_lnproj<<<BB * LL, 384, 0, stream>>>(t, ln1_w + i * CC, ln1_b + i * CC,
                                          ipw + (size_t)i * CC * 2 * DD, xz);
    k_conv<<<(BB * LL * DD + 255) / 256, 256, 0, stream>>>(xz, cw + i * DD * 9, cb + i * DD, xcT);
    k_xproj<<<(BB * KDIR * LL * DBLC + 255) / 256, 256, 0, stream>>>(
        xcT, xpw + (size_t)i * KDIR * DBLC * DD, dbl);
    hipMemsetAsync(ym, 0, (size_t)BB * LL * DD * sizeof(float), stream);
    // one block per chain: 6144 blocks
    k_scan<<<BB * KDIR * DD, 256, 0, stream>>>(
        xcT, dbl, dtw + (size_t)i * KDIR * DD * RRANK, dtb + i * KDIR * DD,
        alog + (size_t)i * KDIR * DD * NSTATE, dsp + i * KDIR * DD, ym);
    k_lngateout<<<BB * LL, DD, 0, stream>>>(ym, onw + i * DD, onb + i * DD, xz,
                                            opw + (size_t)i * DD * CC, t);
  }

  k_final<<<BB, 256, 0, stream>>>(t, nw, nb, hw, hb, out);
}

// Round 6
// 1855.432 us; speedup vs baseline: 2.0278x; 1.0089x over previous
//
#include <hip/hip_runtime.h>
#include <math.h>

#define BB 8
#define IMGS 224
#define PSZ 16
#define CC 96
#define DEPTH 12
#define NCLS 43
#define HH 14
#define WW 14
#define LL 196
#define DD 192
#define NSTATE 16
#define RRANK 6
#define KDIR 4
#define DBLC 38   // R + 2N = 6 + 32 (logical)
#define DBLP 40   // padded row: dt[0..5], pad[6..7], B[8..23], C[24..39]; 160B aligned
#define NSEG 16   // segments per chain (16-lane group each)
#define PTOK 4    // tokens per patch-embed block

__device__ __forceinline__ float wave_sum(float v) {
#pragma unroll
  for (int m = 32; m; m >>= 1) v += __shfl_xor(v, m, 64);
  return v;
}

__device__ __forceinline__ float silu_f(float x) {
  return x / (1.f + __expf(-x));
}

// ---------------- patch embed: 4 tokens/block, LDS-staged patch, contiguous weight reads ----------------
__global__ void k_patch(const float* __restrict__ x, const float* __restrict__ pw,
                        const float* __restrict__ pb, const float* __restrict__ pos,
                        float* __restrict__ t) {
  __shared__ float s_x[PTOK][768];  // 3*16*16 per token
  int tok0 = blockIdx.x * PTOK;
  for (int tk = 0; tk < PTOK; tk++) {
    int tok = tok0 + tk;
    int b = tok / LL, l = tok % LL;
    int ph = l / WW, pwc = l % WW;
    for (int e = threadIdx.x; e < 768; e += 128) {
      int ci = e >> 8, kh = (e >> 4) & 15, kw = e & 15;
      s_x[tk][e] = x[((size_t)(b * 3 + ci) * IMGS + ph * PSZ + kh) * IMGS + pwc * PSZ + kw];
    }
  }
  __syncthreads();
  if (threadIdx.x < CC) {
    int c = threadIdx.x;
    float a0 = pb[c], a1 = a0, a2 = a0, a3 = a0;
    const float* wr = pw + (size_t)c * 768;
    for (int e = 0; e < 768; e++) {
      float wv = wr[e];
      a0 += s_x[0][e] * wv;
      a1 += s_x[1][e] * wv;
      a2 += s_x[2][e] * wv;
      a3 += s_x[3][e] * wv;
    }
    float acc[4] = {a0, a1, a2, a3};
    for (int tk = 0; tk < PTOK; tk++) {
      int tok = tok0 + tk;
      t[(size_t)tok * CC + c] = acc[tk] + pos[(tok % LL) * CC + c];
    }
  }
}

// ---------------- fused LN(96) + in_proj -> xz (B,L,2D); one block (384 thr) per token ----------------
__global__ void k_lnproj(const float* __restrict__ t, const float* __restrict__ w,
                         const float* __restrict__ bias, const float* __restrict__ ipw,
                         float* __restrict__ xz) {
  __shared__ float s_x[CC];
  int tok = blockIdx.x;
  if (threadIdx.x < 64) {
    int lane = threadIdx.x;
    const float* p = t + (size_t)tok * CC;
    float v0 = p[lane];
    float v1 = (lane < CC - 64) ? p[lane + 64] : 0.f;
    float mu = wave_sum(v0 + v1) * (1.f / CC);
    float d0 = v0 - mu;
    float d1 = (lane < CC - 64) ? (v1 - mu) : 0.f;
    float var = wave_sum(d0 * d0 + d1 * d1) * (1.f / CC);
    float rs = rsqrtf(var + 1e-6f);
    s_x[lane] = d0 * rs * w[lane] + bias[lane];
    if (lane < CC - 64) s_x[lane + 64] = d1 * rs * w[lane + 64] + bias[lane + 64];
  }
  __syncthreads();
  int j = threadIdx.x;  // 0..383
  float acc = 0.f;
  for (int c = 0; c < CC; c++) acc += s_x[c] * ipw[(size_t)c * (2 * DD) + j];
  xz[(size_t)tok * (2 * DD) + j] = acc;
}

// ---------------- depthwise 3x3 + bias + SiLU -> xcT (B,L,D); d-fastest, fully coalesced ----------------
__global__ void k_conv(const float* __restrict__ xz, const float* __restrict__ cw,
                       const float* __restrict__ cb, float* __restrict__ xcT) {
  int idx = blockIdx.x * blockDim.x + threadIdx.x;
  if (idx >= BB * LL * DD) return;
  int d = idx % DD;
  int rem = idx / DD;
  int l = rem % LL;
  int b = rem / LL;
  int h = l / WW, w = l % WW;
  float acc = cb[d];
  for (int kh = 0; kh < 3; kh++) {
    int hh = h + kh - 1;
    if (hh < 0 || hh >= HH) continue;
    for (int kw = 0; kw < 3; kw++) {
      int ww = w + kw - 1;
      if (ww < 0 || ww >= WW) continue;
      acc += xz[((size_t)(b * LL + hh * WW + ww)) * (2 * DD) + d] * cw[d * 9 + kh * 3 + kw];
    }
  }
  xcT[((size_t)(b * LL) + l) * DD + d] = silu_f(acc);
}

// ---------------- x_proj: dbl[b,k,l,sc] = sum_d xcT[b,src,d] * xpw[k,c,d]; padded row ----------------
__global__ void k_xproj(const float* __restrict__ xcT, const float* __restrict__ xpw,
                        float* __restrict__ dbl) {
  int idx = blockIdx.x * blockDim.x + threadIdx.x;
  if (idx >= BB * KDIR * LL * DBLC) return;
  int c = idx % DBLC;
  int l = (idx / DBLC) % LL;
  int k = (idx / (DBLC * LL)) % KDIR;
  int b = idx / (DBLC * LL * KDIR);
  int lr = (k >= 2) ? (LL - 1 - l) : l;
  int src = (k & 1) ? ((lr % HH) * WW + lr / HH) : lr;
  const float* xr = xcT + ((size_t)b * LL + src) * DD;
  const float* wp = xpw + ((size_t)k * DBLC + c) * DD;
  float acc = 0.f;
  for (int d = 0; d < DD; d++) acc += xr[d] * wp[d];
  int sc = (c < RRANK) ? c : c + 2;
  dbl[(((size_t)(b * KDIR + k)) * LL + l) * DBLP + sc] = acc;
}

// ---------------- selective scan v4: one BLOCK per (b,k,d) chain, 16 segments ----------------
// Phase 0 (parallel, 196 thr): dt (softplus), src index, xv gather -> LDS.
// Pass 1 (serial 12-13 steps): h = h*exp(dt*A) + dt*xv*B (1 global load); store h in s_h.
// Combine: serial 16-step prefix per state -> h_in per segment.
// Pass 2: P *= a; hf = s_h + P*h_in; y = hf.C (1 global load) + Ds*xv; atomic merge.
__global__ __launch_bounds__(256, 8) void k_scan(
    const float* __restrict__ xcT, const float* __restrict__ dbl,
    const float* __restrict__ dtw, const float* __restrict__ dtb,
    const float* __restrict__ alog, const float* __restrict__ dsv,
    float* __restrict__ ym) {
  __shared__ float s_h[NSTATE][LL + 1];  // stride 197: conflict-free (gcd(5,32)=1)
  __shared__ float s_dt[LL];
  __shared__ float s_xv[LL];
  __shared__ int s_src[LL];
  __shared__ float s_cum[NSEG][NSTATE];
  __shared__ float s_hend[NSEG][NSTATE];
  __shared__ float s_hin[NSEG][NSTATE];
  int tid = threadIdx.x;
  int s = tid >> 4;   // segment 0..15
  int n = tid & 15;   // state
  int g = blockIdx.x; // (b*K + k)*D + d
  int d = g % DD;
  int k = (g / DD) % KDIR;
  int b = g / (DD * KDIR);

  float A = -__expf(alog[((size_t)k * DD + d) * NSTATE + n]);
  float Dsc = dsv[k * DD + d];
  const float* blp = dbl + (size_t)(b * KDIR + k) * LL * DBLP;
  const float* xcb = xcT + (size_t)b * LL * DD + d;

  // ---- phase 0: parallel per-token precompute ----
  if (tid < LL) {
    const float* wp = dtw + ((size_t)k * DD + d) * RRANK;
    int l = tid;
    const float* q = blp + (size_t)l * DBLP;
    float4 q03 = *(const float4*)q;
    float2 q45 = *(const float2*)(q + 4);
    float m = dtb[k * DD + d] + q03.x * wp[0] + q03.y * wp[1] + q03.z * wp[2] +
              q03.w * wp[3] + q45.x * wp[4] + q45.y * wp[5];
    float dtl = (m > 20.f) ? m : __logf(1.f + __expf(m));
    int lr = (k >= 2) ? (LL - 1 - l) : l;
    int src = (k & 1) ? ((lr % HH) * WW + lr / HH) : lr;
    s_dt[l] = dtl;
    s_src[l] = src;
    s_xv[l] = xcb[(size_t)src * DD];
  }
  __syncthreads();

  // segment extents: first 4 segments have 13 steps, rest 12 (4*13 + 12*12 = 196)
  int len = (s < 4) ? 13 : 12;
  int l0 = s * 12 + ((s < 4) ? s : 4);

  // ---- pass 1: local scan from h=0; store h trajectory ----
  float h = 0.f, cum = 1.f;
  for (int i = 0; i < len; i++) {
    int l = l0 + i;
    float dtl = s_dt[l];
    float a = __expf(dtl * A);
    float u = dtl * s_xv[l] * blp[(size_t)l * DBLP + 8 + n];
    h = h * a + u;
    cum *= a;
    s_h[n][l] = h;
  }
  s_cum[s][n] = cum;
  s_hend[s][n] = h;
  __syncthreads();

  // ---- combine: serial 16-step prefix per state (16 threads) ----
  if (tid < NSTATE) {
    float hh = 0.f;
    for (int ss = 0; ss < NSEG; ss++) {
      s_hin[ss][tid] = hh;
      hh = s_cum[ss][tid] * hh + s_hend[ss][tid];
    }
  }
  __syncthreads();

  // ---- pass 2: full state = local + P*h_in; emit y ----
  float hin = s_hin[s][n];
  float P = 1.f;
  float* yo = ym + (size_t)b * LL * DD;
  for (int i = 0; i < len; i++) {
    int l = l0 + i;
    float a = __expf(s_dt[l] * A);
    P *= a;
    float hf = s_h[n][l] + P * hin;
    float part = hf * blp[(size_t)l * DBLP + 24 + n];
    part += __shfl_xor(part, 1, 64);
    part += __shfl_xor(part, 2, 64);
    part += __shfl_xor(part, 4, 64);
    part += __shfl_xor(part, 8, 64);
    if (n == 0) atomicAdd(&yo[(size_t)s_src[l] * DD + d], part + Dsc * s_xv[l]);
  }
}

// ---------------- fused out_norm(192)*silu(z) + out_proj + residual; one block (192 thr)/token ----------------
__global__ void k_lngateout(const float* __restrict__ ym, const float* __restrict__ onw,
                            const float* __restrict__ onb, const float* __restrict__ xz,
                            const float* __restrict__ opw, float* __restrict__ t) {
  __shared__ float s_g[DD];
  __shared__ float s_r[3];
  int tok = blockIdx.x;
  int tid = threadIdx.x;
  int wv = tid >> 6;
  float v = ym[(size_t)tok * DD + tid];
  float p1 = wave_sum(v);
  if ((tid & 63) == 0) s_r[wv] = p1;
  __syncthreads();
  float mu = (s_r[0] + s_r[1] + s_r[2]) * (1.f / DD);
  __syncthreads();
  float dv = v - mu;
  float p2 = wave_sum(dv * dv);
  if ((tid & 63) == 0) s_r[wv] = p2;
  __syncthreads();
  float var = (s_r[0] + s_r[1] + s_r[2]) * (1.f / DD);
  float rs = rsqrtf(var + 1e-6f);
  float zz = xz[(size_t)tok * (2 * DD) + DD + tid];
  s_g[tid] = (dv * rs * onw[tid] + onb[tid]) * silu_f(zz);
  __syncthreads();
  if (tid < CC) {
    float acc = 0.f;
    for (int d = 0; d < DD; d++) acc += s_g[d] * opw[(size_t)d * CC + tid];
    t[(size_t)tok * CC + tid] += acc;
  }
}

// ---------------- fused final LN + mean-pool + head; one block (256 thr) per batch ----------------
__global__ void k_final(const float* __restrict__ t, const float* __restrict__ nw,
                        const float* __restrict__ nb, const float* __restrict__ hw,
                        const float* __restrict__ hb, float* __restrict__ out) {
  __shared__ float s_acc[4][CC];
  __shared__ float s_pool[CC];
  int b = blockIdx.x;
  int wv = threadIdx.x >> 6;
  int lane = threadIdx.x & 63;
  float accA = 0.f, accB = 0.f;
  for (int i = 0; i < 49; i++) {
    int l = wv * 49 + i;
    const float* p = t + ((size_t)b * LL + l) * CC;
    float v0 = p[lane];
    float v1 = (lane < CC - 64) ? p[lane + 64] : 0.f;
    float mu = wave_sum(v0 + v1) * (1.f / CC);
    float d0 = v0 - mu;
    float d1 = (lane < CC - 64) ? (v1 - mu) : 0.f;
    float var = wave_sum(d0 * d0 + d1 * d1) * (1.f / CC);
    float rs = rsqrtf(var + 1e-6f);
    accA += d0 * rs * nw[lane] + nb[lane];
    if (lane < CC - 64) accB += d1 * rs * nw[lane + 64] + nb[lane + 64];
  }
  s_acc[wv][lane] = accA;
  if (lane < CC - 64) s_acc[wv][lane + 64] = accB;
  __syncthreads();
  if (threadIdx.x < CC)
    s_pool[threadIdx.x] = (s_acc[0][threadIdx.x] + s_acc[1][threadIdx.x] +
                           s_acc[2][threadIdx.x] + s_acc[3][threadIdx.x]) * (1.f / LL);
  __syncthreads();
  if (threadIdx.x < NCLS) {
    int j = threadIdx.x;
    float acc = hb[j];
    for (int c = 0; c < CC; c++) acc += s_pool[c] * hw[c * NCLS + j];
    out[b * NCLS + j] = acc;
  }
}

extern "C" void kernel_launch(void* const* d_in, const int* in_sizes, int n_in,
                              void* d_out, int out_size, void* d_ws, size_t ws_size,
                              hipStream_t stream) {
  const float* x       = (const float*)d_in[0];
  const float* patch_w = (const float*)d_in[1];
  const float* patch_b = (const float*)d_in[2];
  const float* pos     = (const float*)d_in[3];
  const float* ln1_w   = (const float*)d_in[4];
  const float* ln1_b   = (const float*)d_in[5];
  const float* ipw     = (const float*)d_in[6];
  const float* cw      = (const float*)d_in[7];
  const float* cb      = (const float*)d_in[8];
  const float* xpw     = (const float*)d_in[9];
  const float* dtw     = (const float*)d_in[10];
  const float* dtb     = (const float*)d_in[11];
  const float* alog    = (const float*)d_in[12];
  const float* dsp     = (const float*)d_in[13];
  const float* onw     = (const float*)d_in[14];
  const float* onb     = (const float*)d_in[15];
  const float* opw     = (const float*)d_in[16];
  const float* nw      = (const float*)d_in[17];
  const float* nb      = (const float*)d_in[18];
  const float* hw      = (const float*)d_in[19];
  const float* hb      = (const float*)d_in[20];
  float* out = (float*)d_out;

  // Workspace: 1,605,632 floats = 6.42 MB
  float* wsf = (float*)d_ws;
  float* t   = wsf;                          // B*L*C    = 150528
  float* xz  = t   + BB * LL * CC;           // B*L*2D   = 602112
  float* xcT = xz  + BB * LL * 2 * DD;       // B*L*D    = 301056
  float* dbl = xcT + BB * LL * DD;           // B*K*L*40 = 250880
  float* ym  = dbl + BB * KDIR * LL * DBLP;  // B*L*D    = 301056

  k_patch<<<BB * LL / PTOK, 128, 0, stream>>>(x, patch_w, patch_b, pos, t);

  for (int i = 0; i < DEPTH; i++) {
    k_lnproj<<<BB * LL, 384, 0, stream>>>(t, ln1_w + i * CC, ln1_b + i * CC,
                                          ipw + (size_t)i * CC * 2 * DD, xz);
    k_conv<<<(BB * LL * DD + 255) / 256, 256, 0, stream>>>(xz, cw + i * DD * 9, cb + i * DD, xcT);
    k_xproj<<<(BB * KDIR * LL * DBLC + 255) / 256, 256, 0, stream>>>(
        xcT, xpw + (size_t)i * KDIR * DBLC * DD, dbl);
    hipMemsetAsync(ym, 0, (size_t)BB * LL * DD * sizeof(float), stream);
    // one block per chain: 6144 blocks
    k_scan<<<BB * KDIR * DD, 256, 0, stream>>>(
        xcT, dbl, dtw + (size_t)i * KDIR * DD * RRANK, dtb + i * KDIR * DD,
        alog + (size_t)i * KDIR * DD * NSTATE, dsp + i * KDIR * DD, ym);
    k_lngateout<<<BB * LL, DD, 0, stream>>>(ym, onw + i * DD, onb + i * DD, xz,
                                            opw + (size_t)i * DD * CC, t);
  }

  k_final<<<BB, 256, 0, stream>>>(t, nw, nb, hw, hb, out);
}

// Round 7
// 1693.731 us; speedup vs baseline: 2.2214x; 1.0955x over previous
//
#include <hip/hip_runtime.h>
#include <math.h>

#define BB 8
#define IMGS 224
#define PSZ 16
#define CC 96
#define DEPTH 12
#define NCLS 43
#define HH 14
#define WW 14
#define LL 196
#define DD 192
#define NSTATE 16
#define RRANK 6
#define KDIR 4
#define DBLC 38   // R + 2N = 6 + 32 (logical)
#define DBLP 40   // padded row: dt[0..5], pad[6..7], B[8..23], C[24..39]; 160B aligned
#define NSEG 16   // segments per chain (16-lane group each)
#define PTOK 4    // tokens per patch-embed block

__device__ __forceinline__ float wave_sum(float v) {
#pragma unroll
  for (int m = 32; m; m >>= 1) v += __shfl_xor(v, m, 64);
  return v;
}

__device__ __forceinline__ float silu_f(float x) {
  return x / (1.f + __expf(-x));
}

// ---------------- patch embed: 4 tokens/block, LDS-staged patch, contiguous weight reads ----------------
__global__ void k_patch(const float* __restrict__ x, const float* __restrict__ pw,
                        const float* __restrict__ pb, const float* __restrict__ pos,
                        float* __restrict__ t) {
  __shared__ float s_x[PTOK][768];  // 3*16*16 per token
  int tok0 = blockIdx.x * PTOK;
  for (int tk = 0; tk < PTOK; tk++) {
    int tok = tok0 + tk;
    int b = tok / LL, l = tok % LL;
    int ph = l / WW, pwc = l % WW;
    for (int e = threadIdx.x; e < 768; e += 128) {
      int ci = e >> 8, kh = (e >> 4) & 15, kw = e & 15;
      s_x[tk][e] = x[((size_t)(b * 3 + ci) * IMGS + ph * PSZ + kh) * IMGS + pwc * PSZ + kw];
    }
  }
  __syncthreads();
  if (threadIdx.x < CC) {
    int c = threadIdx.x;
    float a0 = pb[c], a1 = a0, a2 = a0, a3 = a0;
    const float* wr = pw + (size_t)c * 768;
    for (int e = 0; e < 768; e++) {
      float wv = wr[e];
      a0 += s_x[0][e] * wv;
      a1 += s_x[1][e] * wv;
      a2 += s_x[2][e] * wv;
      a3 += s_x[3][e] * wv;
    }
    float acc[4] = {a0, a1, a2, a3};
    for (int tk = 0; tk < PTOK; tk++) {
      int tok = tok0 + tk;
      t[(size_t)tok * CC + c] = acc[tk] + pos[(tok % LL) * CC + c];
    }
  }
}

// ---------------- fused LN(96) + in_proj -> xz (B,L,2D); one block (384 thr) per token ----------------
__global__ void k_lnproj(const float* __restrict__ t, const float* __restrict__ w,
                         const float* __restrict__ bias, const float* __restrict__ ipw,
                         float* __restrict__ xz) {
  __shared__ float s_x[CC];
  int tok = blockIdx.x;
  if (threadIdx.x < 64) {
    int lane = threadIdx.x;
    const float* p = t + (size_t)tok * CC;
    float v0 = p[lane];
    float v1 = (lane < CC - 64) ? p[lane + 64] : 0.f;
    float mu = wave_sum(v0 + v1) * (1.f / CC);
    float d0 = v0 - mu;
    float d1 = (lane < CC - 64) ? (v1 - mu) : 0.f;
    float var = wave_sum(d0 * d0 + d1 * d1) * (1.f / CC);
    float rs = rsqrtf(var + 1e-6f);
    s_x[lane] = d0 * rs * w[lane] + bias[lane];
    if (lane < CC - 64) s_x[lane + 64] = d1 * rs * w[lane + 64] + bias[lane + 64];
  }
  __syncthreads();
  int j = threadIdx.x;  // 0..383
  float acc = 0.f;
  for (int c = 0; c < CC; c++) acc += s_x[c] * ipw[(size_t)c * (2 * DD) + j];
  xz[(size_t)tok * (2 * DD) + j] = acc;
}

// ---------------- depthwise 3x3 + bias + SiLU -> xcT (B,L,D); d-fastest, fully coalesced ----------------
__global__ void k_conv(const float* __restrict__ xz, const float* __restrict__ cw,
                       const float* __restrict__ cb, float* __restrict__ xcT) {
  int idx = blockIdx.x * blockDim.x + threadIdx.x;
  if (idx >= BB * LL * DD) return;
  int d = idx % DD;
  int rem = idx / DD;
  int l = rem % LL;
  int b = rem / LL;
  int h = l / WW, w = l % WW;
  float acc = cb[d];
  for (int kh = 0; kh < 3; kh++) {
    int hh = h + kh - 1;
    if (hh < 0 || hh >= HH) continue;
    for (int kw = 0; kw < 3; kw++) {
      int ww = w + kw - 1;
      if (ww < 0 || ww >= WW) continue;
      acc += xz[((size_t)(b * LL + hh * WW + ww)) * (2 * DD) + d] * cw[d * 9 + kh * 3 + kw];
    }
  }
  xcT[((size_t)(b * LL) + l) * DD + d] = silu_f(acc);
}

// ---------------- x_proj: dbl[b,k,l,sc] = sum_d xcT[b,src,d] * xpw[k,c,d]; padded row ----------------
__global__ void k_xproj(const float* __restrict__ xcT, const float* __restrict__ xpw,
                        float* __restrict__ dbl) {
  int idx = blockIdx.x * blockDim.x + threadIdx.x;
  if (idx >= BB * KDIR * LL * DBLC) return;
  int c = idx % DBLC;
  int l = (idx / DBLC) % LL;
  int k = (idx / (DBLC * LL)) % KDIR;
  int b = idx / (DBLC * LL * KDIR);
  int lr = (k >= 2) ? (LL - 1 - l) : l;
  int src = (k & 1) ? ((lr % HH) * WW + lr / HH) : lr;
  const float* xr = xcT + ((size_t)b * LL + src) * DD;
  const float* wp = xpw + ((size_t)k * DBLC + c) * DD;
  float acc = 0.f;
  for (int d = 0; d < DD; d++) acc += xr[d] * wp[d];
  int sc = (c < RRANK) ? c : c + 2;
  dbl[(((size_t)(b * KDIR + k)) * LL + l) * DBLP + sc] = acc;
}

// ---------------- selective scan v5: one BLOCK per (b,k,d) chain ----------------
// Phase 0 (parallel 196 thr): dt, u=dt*xv, src, xv, per-segment prefix-sum cumdt -> LDS.
// Pass 1 (only serial part): h = h*exp(dt*A) + u*B, B prefetched to registers; store s_h[n][l].
// Combine: 16 lanes x 16 serial steps; cum = exp(A*segsum).
// Phase 2 (parallel, 1 thr/token): y_l = sum_n (s_h[n][l] + exp(A_n*cumdt_l)*hin[seg][n])*C_ln
//                                        + Ds*xv_l ; one atomic per token. No shuffles anywhere.
__global__ __launch_bounds__(256, 8) void k_scan(
    const float* __restrict__ xcT, const float* __restrict__ dbl,
    const float* __restrict__ dtw, const float* __restrict__ dtb,
    const float* __restrict__ alog, const float* __restrict__ dsv,
    float* __restrict__ ym) {
  __shared__ float s_h[NSTATE][LL + 1];  // stride 197: conflict-free (gcd(5,32)=1)
  __shared__ float s_dt[LL];
  __shared__ float s_u[LL];
  __shared__ float s_xv[LL];
  __shared__ float s_cumdt[LL];
  __shared__ int s_src[LL];
  __shared__ float s_hin[NSEG][NSTATE];
  __shared__ float s_hend[NSEG][NSTATE];
  __shared__ float s_segsum[NSEG];
  __shared__ float s_A[NSTATE];
  int tid = threadIdx.x;
  int s = tid >> 4;   // segment 0..15
  int n = tid & 15;   // state
  int g = blockIdx.x; // (b*K + k)*D + d
  int d = g % DD;
  int k = (g / DD) % KDIR;
  int b = g / (DD * KDIR);

  float A = -__expf(alog[((size_t)k * DD + d) * NSTATE + n]);
  float Dsc = dsv[k * DD + d];
  const float* blp = dbl + (size_t)(b * KDIR + k) * LL * DBLP;
  const float* xcb = xcT + (size_t)b * LL * DD + d;
  if (tid < NSTATE) s_A[tid] = A;

  // segment extents: first 4 have 13 steps, rest 12 (4*13 + 12*12 = 196)
  int len = (s < 4) ? 13 : 12;
  int l0 = s * 12 + ((s < 4) ? s : 4);

  // ---- phase 0: parallel per-token precompute ----
  if (tid < LL) {
    const float* wp = dtw + ((size_t)k * DD + d) * RRANK;
    int l = tid;
    const float* q = blp + (size_t)l * DBLP;
    float4 q03 = *(const float4*)q;
    float2 q45 = *(const float2*)(q + 4);
    float m = dtb[k * DD + d] + q03.x * wp[0] + q03.y * wp[1] + q03.z * wp[2] +
              q03.w * wp[3] + q45.x * wp[4] + q45.y * wp[5];
    float dtl = (m > 20.f) ? m : __logf(1.f + __expf(m));
    int lr = (k >= 2) ? (LL - 1 - l) : l;
    int src = (k & 1) ? ((lr % HH) * WW + lr / HH) : lr;
    float xv = xcb[(size_t)src * DD];
    s_dt[l] = dtl;
    s_src[l] = src;
    s_xv[l] = xv;
    s_u[l] = dtl * xv;
  }
  __syncthreads();

  // per-token inclusive prefix sum of dt within its segment (parallel over tokens)
  if (tid < LL) {
    int l = tid;
    int myseg = (l < 52) ? (l / 13) : (4 + (l - 52) / 12);
    int sl0 = myseg * 12 + ((myseg < 4) ? myseg : 4);
    float acc = 0.f;
    for (int j = sl0; j <= l; j++) acc += s_dt[j];
    s_cumdt[l] = acc;
    int slen = (myseg < 4) ? 13 : 12;
    if (l == sl0 + slen - 1) s_segsum[myseg] = acc;
  }
  __syncthreads();

  // ---- pass 1: serial local scan from h=0 (B prefetched to registers) ----
  float Breg[13];
#pragma unroll
  for (int i = 0; i < 13; i++) {
    int li = (i < len) ? (l0 + i) : l0;
    Breg[i] = blp[(size_t)li * DBLP + 8 + n];
  }
  float h = 0.f;
#pragma unroll
  for (int i = 0; i < 13; i++) {
    if (i < len) {
      int l = l0 + i;
      float a = __expf(s_dt[l] * A);
      h = h * a + s_u[l] * Breg[i];
      s_h[n][l] = h;
    }
  }
  s_hend[s][n] = h;
  __syncthreads();

  // ---- combine: serial 16-step prefix per state (16 threads) ----
  if (tid < NSTATE) {
    float hh = 0.f;
    for (int ss = 0; ss < NSEG; ss++) {
      s_hin[ss][tid] = hh;
      hh = __expf(A * s_segsum[ss]) * hh + s_hend[ss][tid];
    }
  }
  __syncthreads();

  // ---- phase 2: fully parallel y per token ----
  if (tid < LL) {
    int l = tid;
    int myseg = (l < 52) ? (l / 13) : (4 + (l - 52) / 12);
    float cd = s_cumdt[l];
    const float* q = blp + (size_t)l * DBLP + 24;  // C row, 16 floats
    float y = 0.f;
#pragma unroll
    for (int nn = 0; nn < NSTATE; nn++) {
      float hf = s_h[nn][l] + __expf(s_A[nn] * cd) * s_hin[myseg][nn];
      y += hf * q[nn];
    }
    y += Dsc * s_xv[l];
    atomicAdd(&ym[((size_t)b * LL + s_src[l]) * DD + d], y);
  }
}

// ---------------- fused out_norm(192)*silu(z) + out_proj + residual; one block (192 thr)/token ----------------
__global__ void k_lngateout(const float* __restrict__ ym, const float* __restrict__ onw,
                            const float* __restrict__ onb, const float* __restrict__ xz,
                            const float* __restrict__ opw, float* __restrict__ t) {
  __shared__ float s_g[DD];
  __shared__ float s_r[3];
  int tok = blockIdx.x;
  int tid = threadIdx.x;
  int wv = tid >> 6;
  float v = ym[(size_t)tok * DD + tid];
  float p1 = wave_sum(v);
  if ((tid & 63) == 0) s_r[wv] = p1;
  __syncthreads();
  float mu = (s_r[0] + s_r[1] + s_r[2]) * (1.f / DD);
  __syncthreads();
  float dv = v - mu;
  float p2 = wave_sum(dv * dv);
  if ((tid & 63) == 0) s_r[wv] = p2;
  __syncthreads();
  float var = (s_r[0] + s_r[1] + s_r[2]) * (1.f / DD);
  float rs = rsqrtf(var + 1e-6f);
  float zz = xz[(size_t)tok * (2 * DD) + DD + tid];
  s_g[tid] = (dv * rs * onw[tid] + onb[tid]) * silu_f(zz);
  __syncthreads();
  if (tid < CC) {
    float acc = 0.f;
    for (int d = 0; d < DD; d++) acc += s_g[d] * opw[(size_t)d * CC + tid];
    t[(size_t)tok * CC + tid] += acc;
  }
}

// ---------------- fused final LN + mean-pool + head; one block (256 thr) per batch ----------------
__global__ void k_final(const float* __restrict__ t, const float* __restrict__ nw,
                        const float* __restrict__ nb, const float* __restrict__ hw,
                        const float* __restrict__ hb, float* __restrict__ out) {
  __shared__ float s_acc[4][CC];
  __shared__ float s_pool[CC];
  int b = blockIdx.x;
  int wv = threadIdx.x >> 6;
  int lane = threadIdx.x & 63;
  float accA = 0.f, accB = 0.f;
  for (int i = 0; i < 49; i++) {
    int l = wv * 49 + i;
    const float* p = t + ((size_t)b * LL + l) * CC;
    float v0 = p[lane];
    float v1 = (lane < CC - 64) ? p[lane + 64] : 0.f;
    float mu = wave_sum(v0 + v1) * (1.f / CC);
    float d0 = v0 - mu;
    float d1 = (lane < CC - 64) ? (v1 - mu) : 0.f;
    float var = wave_sum(d0 * d0 + d1 * d1) * (1.f / CC);
    float rs = rsqrtf(var + 1e-6f);
    accA += d0 * rs * nw[lane] + nb[lane];
    if (lane < CC - 64) accB += d1 * rs * nw[lane + 64] + nb[lane + 64];
  }
  s_acc[wv][lane] = accA;
  if (lane < CC - 64) s_acc[wv][lane + 64] = accB;
  __syncthreads();
  if (threadIdx.x < CC)
    s_pool[threadIdx.x] = (s_acc[0][threadIdx.x] + s_acc[1][threadIdx.x] +
                           s_acc[2][threadIdx.x] + s_acc[3][threadIdx.x]) * (1.f / LL);
  __syncthreads();
  if (threadIdx.x < NCLS) {
    int j = threadIdx.x;
    float acc = hb[j];
    for (int c = 0; c < CC; c++) acc += s_pool[c] * hw[c * NCLS + j];
    out[b * NCLS + j] = acc;
  }
}

extern "C" void kernel_launch(void* const* d_in, const int* in_sizes, int n_in,
                              void* d_out, int out_size, void* d_ws, size_t ws_size,
                              hipStream_t stream) {
  const float* x       = (const float*)d_in[0];
  const float* patch_w = (const float*)d_in[1];
  const float* patch_b = (const float*)d_in[2];
  const float* pos     = (const float*)d_in[3];
  const float* ln1_w   = (const float*)d_in[4];
  const float* ln1_b   = (const float*)d_in[5];
  const float* ipw     = (const float*)d_in[6];
  const float* cw      = (const float*)d_in[7];
  const float* cb      = (const float*)d_in[8];
  const float* xpw     = (const float*)d_in[9];
  const float* dtw     = (const float*)d_in[10];
  const float* dtb     = (const float*)d_in[11];
  const float* alog    = (const float*)d_in[12];
  const float* dsp     = (const float*)d_in[13];
  const float* onw     = (const float*)d_in[14];
  const float* onb     = (const float*)d_in[15];
  const float* opw     = (const float*)d_in[16];
  const float* nw      = (const float*)d_in[17];
  const float* nb      = (const float*)d_in[18];
  const float* hw      = (const float*)d_in[19];
  const float* hb      = (const float*)d_in[20];
  float* out = (float*)d_out;

  // Workspace: 1,605,632 floats = 6.42 MB
  float* wsf = (float*)d_ws;
  float* t   = wsf;                          // B*L*C    = 150528
  float* xz  = t   + BB * LL * CC;           // B*L*2D   = 602112
  float* xcT = xz  + BB * LL * 2 * DD;       // B*L*D    = 301056
  float* dbl = xcT + BB * LL * DD;           // B*K*L*40 = 250880
  float* ym  = dbl + BB * KDIR * LL * DBLP;  // B*L*D    = 301056

  k_patch<<<BB * LL / PTOK, 128, 0, stream>>>(x, patch_w, patch_b, pos, t);

  for (int i = 0; i < DEPTH; i++) {
    k_lnproj<<<BB * LL, 384, 0, stream>>>(t, ln1_w + i * CC, ln1_b + i * CC,
                                          ipw + (size_t)i * CC * 2 * DD, xz);
    k_conv<<<(BB * LL * DD + 255) / 256, 256, 0, stream>>>(xz, cw + i * DD * 9, cb + i * DD, xcT);
    k_xproj<<<(BB * KDIR * LL * DBLC + 255) / 256, 256, 0, stream>>>(
        xcT, xpw + (size_t)i * KDIR * DBLC * DD, dbl);
    hipMemsetAsync(ym, 0, (size_t)BB * LL * DD * sizeof(float), stream);
    // one block per chain: 6144 blocks
    k_scan<<<BB * KDIR * DD, 256, 0, stream>>>(
        xcT, dbl, dtw + (size_t)i * KDIR * DD * RRANK, dtb + i * KDIR * DD,
        alog + (size_t)i * KDIR * DD * NSTATE, dsp + i * KDIR * DD, ym);
    k_lngateout<<<BB * LL, DD, 0, stream>>>(ym, onw + i * DD, onb + i * DD, xz,
                                            opw + (size_t)i * DD * CC, t);
  }

  k_final<<<BB, 256, 0, stream>>>(t, nw, nb, hw, hb, out);
}

// Round 8
// 1666.695 us; speedup vs baseline: 2.2574x; 1.0162x over previous
//
#include <hip/hip_runtime.h>
#include <math.h>

#define BB 8
#define IMGS 224
#define PSZ 16
#define CC 96
#define DEPTH 12
#define NCLS 43
#define HH 14
#define WW 14
#define LL 196
#define DD 192
#define NSTATE 16
#define RRANK 6
#define KDIR 4
#define DBLC 38     // R + 2N = 6 + 32 (logical outputs of x_proj)
#define NSEG 16     // segments per chain
#define PTOK 4      // tokens per patch-embed block
// per-(b,k) dbl region: dtT[6][200] + B[196][16] + Ct[16][200]
#define TSTR 200    // row stride for dtT / Ct
#define OFF_B 1200
#define OFF_C 4336
#define DBKSZ 7552  // 1200 + 3136 + 3200 + 16 pad

__device__ __forceinline__ float wave_sum(float v) {
#pragma unroll
  for (int m = 32; m; m >>= 1) v += __shfl_xor(v, m, 64);
  return v;
}

__device__ __forceinline__ float silu_f(float x) {
  return x / (1.f + __expf(-x));
}

// ---------------- patch embed: 4 tokens/block, LDS-staged patch, contiguous weight reads ----------------
__global__ void k_patch(const float* __restrict__ x, const float* __restrict__ pw,
                        const float* __restrict__ pb, const float* __restrict__ pos,
                        float* __restrict__ t) {
  __shared__ float s_x[PTOK][768];  // 3*16*16 per token
  int tok0 = blockIdx.x * PTOK;
  for (int tk = 0; tk < PTOK; tk++) {
    int tok = tok0 + tk;
    int b = tok / LL, l = tok % LL;
    int ph = l / WW, pwc = l % WW;
    for (int e = threadIdx.x; e < 768; e += 128) {
      int ci = e >> 8, kh = (e >> 4) & 15, kw = e & 15;
      s_x[tk][e] = x[((size_t)(b * 3 + ci) * IMGS + ph * PSZ + kh) * IMGS + pwc * PSZ + kw];
    }
  }
  __syncthreads();
  if (threadIdx.x < CC) {
    int c = threadIdx.x;
    float a0 = pb[c], a1 = a0, a2 = a0, a3 = a0;
    const float* wr = pw + (size_t)c * 768;
    for (int e = 0; e < 768; e++) {
      float wv = wr[e];
      a0 += s_x[0][e] * wv;
      a1 += s_x[1][e] * wv;
      a2 += s_x[2][e] * wv;
      a3 += s_x[3][e] * wv;
    }
    float acc[4] = {a0, a1, a2, a3};
    for (int tk = 0; tk < PTOK; tk++) {
      int tok = tok0 + tk;
      t[(size_t)tok * CC + c] = acc[tk] + pos[(tok % LL) * CC + c];
    }
  }
}

// ---------------- fused LN(96) + in_proj -> xz (B,L,2D); one block (384 thr) per token ----------------
__global__ void k_lnproj(const float* __restrict__ t, const float* __restrict__ w,
                         const float* __restrict__ bias, const float* __restrict__ ipw,
                         float* __restrict__ xz) {
  __shared__ float s_x[CC];
  int tok = blockIdx.x;
  if (threadIdx.x < 64) {
    int lane = threadIdx.x;
    const float* p = t + (size_t)tok * CC;
    float v0 = p[lane];
    float v1 = (lane < CC - 64) ? p[lane + 64] : 0.f;
    float mu = wave_sum(v0 + v1) * (1.f / CC);
    float d0 = v0 - mu;
    float d1 = (lane < CC - 64) ? (v1 - mu) : 0.f;
    float var = wave_sum(d0 * d0 + d1 * d1) * (1.f / CC);
    float rs = rsqrtf(var + 1e-6f);
    s_x[lane] = d0 * rs * w[lane] + bias[lane];
    if (lane < CC - 64) s_x[lane + 64] = d1 * rs * w[lane + 64] + bias[lane + 64];
  }
  __syncthreads();
  int j = threadIdx.x;  // 0..383
  float acc = 0.f;
  for (int c = 0; c < CC; c++) acc += s_x[c] * ipw[(size_t)c * (2 * DD) + j];
  xz[(size_t)tok * (2 * DD) + j] = acc;
}

// ---------------- depthwise 3x3 + bias + SiLU -> xcT (B,L,D); d-fastest, fully coalesced ----------------
__global__ void k_conv(const float* __restrict__ xz, const float* __restrict__ cw,
                       const float* __restrict__ cb, float* __restrict__ xcT) {
  int idx = blockIdx.x * blockDim.x + threadIdx.x;
  if (idx >= BB * LL * DD) return;
  int d = idx % DD;
  int rem = idx / DD;
  int l = rem % LL;
  int b = rem / LL;
  int h = l / WW, w = l % WW;
  float acc = cb[d];
  for (int kh = 0; kh < 3; kh++) {
    int hh = h + kh - 1;
    if (hh < 0 || hh >= HH) continue;
    for (int kw = 0; kw < 3; kw++) {
      int ww = w + kw - 1;
      if (ww < 0 || ww >= WW) continue;
      acc += xz[((size_t)(b * LL + hh * WW + ww)) * (2 * DD) + d] * cw[d * 9 + kh * 3 + kw];
    }
  }
  xcT[((size_t)(b * LL) + l) * DD + d] = silu_f(acc);
}

// ---------------- x_proj -> split layout: dtT[6][200] r-major, B[196][16], Ct[16][200] ----------------
__global__ void k_xproj(const float* __restrict__ xcT, const float* __restrict__ xpw,
                        float* __restrict__ dbl) {
  int idx = blockIdx.x * blockDim.x + threadIdx.x;
  if (idx >= BB * KDIR * LL * DBLC) return;
  int c = idx % DBLC;
  int l = (idx / DBLC) % LL;
  int k = (idx / (DBLC * LL)) % KDIR;
  int b = idx / (DBLC * LL * KDIR);
  int lr = (k >= 2) ? (LL - 1 - l) : l;
  int src = (k & 1) ? ((lr % HH) * WW + lr / HH) : lr;
  const float4* xr = (const float4*)(xcT + ((size_t)b * LL + src) * DD);
  const float4* wp = (const float4*)(xpw + ((size_t)k * DBLC + c) * DD);
  float acc = 0.f;
#pragma unroll 8
  for (int d4 = 0; d4 < DD / 4; d4++) {
    float4 a = xr[d4], w = wp[d4];
    acc += a.x * w.x + a.y * w.y + a.z * w.z + a.w * w.w;
  }
  float* base = dbl + (size_t)(b * KDIR + k) * DBKSZ;
  if (c < RRANK) base[c * TSTR + l] = acc;                 // dt inputs, r-major
  else if (c < RRANK + NSTATE) base[OFF_B + l * NSTATE + (c - RRANK)] = acc;  // B, l-major
  else base[OFF_C + (c - RRANK - NSTATE) * TSTR + l] = acc;                   // C, c-major
}

// ---------------- selective scan v6: one BLOCK per (b,k,d) chain; coalesced sub-buffers ----------------
// Phase 0 (parallel 196 thr): dt from r-major rows (coalesced), u=dt*xv, src, xv, seg prefix of dt.
// Pass 1 (only serial part): h = h*exp(dt*A) + u*B, B prefetched; store s_h[n][l].
// Combine: 16 lanes x 16 serial steps; cum = exp(A*segsum).
// Phase 2 (parallel, 1 thr/token): y_l = sum_n (s_h[n][l] + exp(A_n*cumdt_l)*hin[seg][n])*Ct[n][l]
//                                  (coalesced) + Ds*xv_l ; one atomic per token.
__global__ __launch_bounds__(256, 8) void k_scan(
    const float* __restrict__ xcT, const float* __restrict__ dbl,
    const float* __restrict__ dtw, const float* __restrict__ dtb,
    const float* __restrict__ alog, const float* __restrict__ dsv,
    float* __restrict__ ym) {
  __shared__ float s_h[NSTATE][LL + 1];  // stride 197: conflict-free (gcd(5,32)=1)
  __shared__ float s_dt[LL];
  __shared__ float s_u[LL];
  __shared__ float s_xv[LL];
  __shared__ float s_cumdt[LL];
  __shared__ int s_src[LL];
  __shared__ float s_hin[NSEG][NSTATE];
  __shared__ float s_hend[NSEG][NSTATE];
  __shared__ float s_segsum[NSEG];
  __shared__ float s_A[NSTATE];
  int tid = threadIdx.x;
  int s = tid >> 4;   // segment 0..15
  int n = tid & 15;   // state
  int g = blockIdx.x; // (b*K + k)*D + d
  int d = g % DD;
  int k = (g / DD) % KDIR;
  int b = g / (DD * KDIR);

  float A = -__expf(alog[((size_t)k * DD + d) * NSTATE + n]);
  float Dsc = dsv[k * DD + d];
  const float* blp = dbl + (size_t)(b * KDIR + k) * DBKSZ;
  const float* xcb = xcT + (size_t)b * LL * DD + d;
  if (tid < NSTATE) s_A[tid] = A;

  // segment extents: first 4 have 13 steps, rest 12 (4*13 + 12*12 = 196)
  int len = (s < 4) ? 13 : 12;
  int l0 = s * 12 + ((s < 4) ? s : 4);

  // ---- phase 0: parallel per-token precompute (dt rows now coalesced) ----
  if (tid < LL) {
    const float* wp = dtw + ((size_t)k * DD + d) * RRANK;
    int l = tid;
    float m = dtb[k * DD + d];
#pragma unroll
    for (int r = 0; r < RRANK; r++) m += blp[r * TSTR + l] * wp[r];
    float dtl = (m > 20.f) ? m : __logf(1.f + __expf(m));
    int lr = (k >= 2) ? (LL - 1 - l) : l;
    int src = (k & 1) ? ((lr % HH) * WW + lr / HH) : lr;
    float xv = xcb[(size_t)src * DD];
    s_dt[l] = dtl;
    s_src[l] = src;
    s_xv[l] = xv;
    s_u[l] = dtl * xv;
  }
  __syncthreads();

  // per-token inclusive prefix sum of dt within its segment
  if (tid < LL) {
    int l = tid;
    int myseg = (l < 52) ? (l / 13) : (4 + (l - 52) / 12);
    int sl0 = myseg * 12 + ((myseg < 4) ? myseg : 4);
    float acc = 0.f;
    for (int j = sl0; j <= l; j++) acc += s_dt[j];
    s_cumdt[l] = acc;
    int slen = (myseg < 4) ? 13 : 12;
    if (l == sl0 + slen - 1) s_segsum[myseg] = acc;
  }
  __syncthreads();

  // ---- pass 1: serial local scan from h=0 (B prefetched to registers) ----
  float Breg[13];
#pragma unroll
  for (int i = 0; i < 13; i++) {
    int li = (i < len) ? (l0 + i) : l0;
    Breg[i] = blp[OFF_B + li * NSTATE + n];
  }
  float h = 0.f;
#pragma unroll
  for (int i = 0; i < 13; i++) {
    if (i < len) {
      int l = l0 + i;
      float a = __expf(s_dt[l] * A);
      h = h * a + s_u[l] * Breg[i];
      s_h[n][l] = h;
    }
  }
  s_hend[s][n] = h;
  __syncthreads();

  // ---- combine: serial 16-step prefix per state (16 threads) ----
  if (tid < NSTATE) {
    float hh = 0.f;
    for (int ss = 0; ss < NSEG; ss++) {
      s_hin[ss][tid] = hh;
      hh = __expf(A * s_segsum[ss]) * hh + s_hend[ss][tid];
    }
  }
  __syncthreads();

  // ---- phase 2: fully parallel y per token (C reads coalesced c-major) ----
  if (tid < LL) {
    int l = tid;
    int myseg = (l < 52) ? (l / 13) : (4 + (l - 52) / 12);
    float cd = s_cumdt[l];
    const float* q = blp + OFF_C + l;  // Ct[nn][l], stride TSTR
    float y = 0.f;
#pragma unroll
    for (int nn = 0; nn < NSTATE; nn++) {
      float hf = s_h[nn][l] + __expf(s_A[nn] * cd) * s_hin[myseg][nn];
      y += hf * q[nn * TSTR];
    }
    y += Dsc * s_xv[l];
    atomicAdd(&ym[((size_t)b * LL + s_src[l]) * DD + d], y);
  }
}

// ---------------- fused out_norm(192)*silu(z) + out_proj + residual; one block (192 thr)/token ----------------
__global__ void k_lngateout(const float* __restrict__ ym, const float* __restrict__ onw,
                            const float* __restrict__ onb, const float* __restrict__ xz,
                            const float* __restrict__ opw, float* __restrict__ t) {
  __shared__ float s_g[DD];
  __shared__ float s_r[3];
  int tok = blockIdx.x;
  int tid = threadIdx.x;
  int wv = tid >> 6;
  float v = ym[(size_t)tok * DD + tid];
  float p1 = wave_sum(v);
  if ((tid & 63) == 0) s_r[wv] = p1;
  __syncthreads();
  float mu = (s_r[0] + s_r[1] + s_r[2]) * (1.f / DD);
  __syncthreads();
  float dv = v - mu;
  float p2 = wave_sum(dv * dv);
  if ((tid & 63) == 0) s_r[wv] = p2;
  __syncthreads();
  float var = (s_r[0] + s_r[1] + s_r[2]) * (1.f / DD);
  float rs = rsqrtf(var + 1e-6f);
  float zz = xz[(size_t)tok * (2 * DD) + DD + tid];
  s_g[tid] = (dv * rs * onw[tid] + onb[tid]) * silu_f(zz);
  __syncthreads();
  if (tid < CC) {
    float acc = 0.f;
    for (int d = 0; d < DD; d++) acc += s_g[d] * opw[(size_t)d * CC + tid];
    t[(size_t)tok * CC + tid] += acc;
  }
}

// ---------------- fused final LN + mean-pool + head; one block (256 thr) per batch ----------------
__global__ void k_final(const float* __restrict__ t, const float* __restrict__ nw,
                        const float* __restrict__ nb, const float* __restrict__ hw,
                        const float* __restrict__ hb, float* __restrict__ out) {
  __shared__ float s_acc[4][CC];
  __shared__ float s_pool[CC];
  int b = blockIdx.x;
  int wv = threadIdx.x >> 6;
  int lane = threadIdx.x & 63;
  float accA = 0.f, accB = 0.f;
  for (int i = 0; i < 49; i++) {
    int l = wv * 49 + i;
    const float* p = t + ((size_t)b * LL + l) * CC;
    float v0 = p[lane];
    float v1 = (lane < CC - 64) ? p[lane + 64] : 0.f;
    float mu = wave_sum(v0 + v1) * (1.f / CC);
    float d0 = v0 - mu;
    float d1 = (lane < CC - 64) ? (v1 - mu) : 0.f;
    float var = wave_sum(d0 * d0 + d1 * d1) * (1.f / CC);
    float rs = rsqrtf(var + 1e-6f);
    accA += d0 * rs * nw[lane] + nb[lane];
    if (lane < CC - 64) accB += d1 * rs * nw[lane + 64] + nb[lane + 64];
  }
  s_acc[wv][lane] = accA;
  if (lane < CC - 64) s_acc[wv][lane + 64] = accB;
  __syncthreads();
  if (threadIdx.x < CC)
    s_pool[threadIdx.x] = (s_acc[0][threadIdx.x] + s_acc[1][threadIdx.x] +
                           s_acc[2][threadIdx.x] + s_acc[3][threadIdx.x]) * (1.f / LL);
  __syncthreads();
  if (threadIdx.x < NCLS) {
    int j = threadIdx.x;
    float acc = hb[j];
    for (int c = 0; c < CC; c++) acc += s_pool[c] * hw[c * NCLS + j];
    out[b * NCLS + j] = acc;
  }
}

extern "C" void kernel_launch(void* const* d_in, const int* in_sizes, int n_in,
                              void* d_out, int out_size, void* d_ws, size_t ws_size,
                              hipStream_t stream) {
  const float* x       = (const float*)d_in[0];
  const float* patch_w = (const float*)d_in[1];
  const float* patch_b = (const float*)d_in[2];
  const float* pos     = (const float*)d_in[3];
  const float* ln1_w   = (const float*)d_in[4];
  const float* ln1_b   = (const float*)d_in[5];
  const float* ipw     = (const float*)d_in[6];
  const float* cw      = (const float*)d_in[7];
  const float* cb      = (const float*)d_in[8];
  const float* xpw     = (const float*)d_in[9];
  const float* dtw     = (const float*)d_in[10];
  const float* dtb     = (const float*)d_in[11];
  const float* alog    = (const float*)d_in[12];
  const float* dsp     = (const float*)d_in[13];
  const float* onw     = (const float*)d_in[14];
  const float* onb     = (const float*)d_in[15];
  const float* opw     = (const float*)d_in[16];
  const float* nw      = (const float*)d_in[17];
  const float* nb      = (const float*)d_in[18];
  const float* hw      = (const float*)d_in[19];
  const float* hb      = (const float*)d_in[20];
  float* out = (float*)d_out;

  // Workspace: t 150528 + xz 602112 + xcT 301056 + dbl 32*7552=241664 + ym 301056 = 1,596,416 fl = 6.39 MB
  float* wsf = (float*)d_ws;
  float* t   = wsf;                          // B*L*C
  float* xz  = t   + BB * LL * CC;           // B*L*2D
  float* xcT = xz  + BB * LL * 2 * DD;       // B*L*D
  float* dbl = xcT + BB * LL * DD;           // 32 * DBKSZ
  float* ym  = dbl + BB * KDIR * DBKSZ;      // B*L*D

  k_patch<<<BB * LL / PTOK, 128, 0, stream>>>(x, patch_w, patch_b, pos, t);

  for (int i = 0; i < DEPTH; i++) {
    k_lnproj<<<BB * LL, 384, 0, stream>>>(t, ln1_w + i * CC, ln1_b + i * CC,
                                          ipw + (size_t)i * CC * 2 * DD, xz);
    k_conv<<<(BB * LL * DD + 255) / 256, 256, 0, stream>>>(xz, cw + i * DD * 9, cb + i * DD, xcT);
    k_xproj<<<(BB * KDIR * LL * DBLC + 255) / 256, 256, 0, stream>>>(
        xcT, xpw + (size_t)i * KDIR * DBLC * DD, dbl);
    hipMemsetAsync(ym, 0, (size_t)BB * LL * DD * sizeof(float), stream);
    // one block per chain: 6144 blocks
    k_scan<<<BB * KDIR * DD, 256, 0, stream>>>(
        xcT, dbl, dtw + (size_t)i * KDIR * DD * RRANK, dtb + i * KDIR * DD,
        alog + (size_t)i * KDIR * DD * NSTATE, dsp + i * KDIR * DD, ym);
    k_lngateout<<<BB * LL, DD, 0, stream>>>(ym, onw + i * DD, onb + i * DD, xz,
                                            opw + (size_t)i * DD * CC, t);
  }

  k_final<<<BB, 256, 0, stream>>>(t, nw, nb, hw, hb, out);
}